// Round 1
// baseline (880.742 us; speedup 1.0000x reference)
//
#include <hip/hip_runtime.h>
#include <stdint.h>

#define N_NODES 3072
#define D_IN    256
#define HIDDEN  384
#define HEADS   6
#define NH1     64
#define C1      1152   // 3*HIDDEN
#define C2      768    // 3*D_IN
#define MASK_ULL   48  // 3072/64 per row
#define MASK_BYTES 384 // 3072/8 per row

typedef __bf16 bf16;
typedef __bf16 bf16x8 __attribute__((ext_vector_type(8)));
typedef __bf16 bf16x4 __attribute__((ext_vector_type(4)));
typedef float  f32x4  __attribute__((ext_vector_type(4)));

// ---------------------------------------------------------------- cast fp32->bf16
struct CastArgs {
  const float* src[11];
  bf16*        dst[11];
  int          cum4[12];   // cumulative count/4 boundaries
};

__global__ __launch_bounds__(256) void cast_all_kernel(CastArgs A) {
  int g = blockIdx.x * 256 + threadIdx.x;
  int j = 0;
#pragma unroll
  for (int k = 1; k < 11; ++k) j += (g >= A.cum4[k]);
  int e = (g - A.cum4[j]) * 4;
  float4 v = *(const float4*)(A.src[j] + e);
  bf16x4 o = { (bf16)v.x, (bf16)v.y, (bf16)v.z, (bf16)v.w };
  *(bf16x4*)(A.dst[j] + e) = o;
}

// ---------------------------------------------------------------- adj -> bitmask
__global__ __launch_bounds__(256) void pack_adj_kernel(const int* __restrict__ adj,
                                                       unsigned long long* __restrict__ maskU) {
  int row = blockIdx.x;
  const int* ar = adj + (size_t)row * N_NODES;
  int lane = threadIdx.x & 63, wave = threadIdx.x >> 6;
#pragma unroll
  for (int it = 0; it < N_NODES / 256; ++it) {
    int j = it * 256 + wave * 64 + lane;
    unsigned long long b = __ballot(ar[j] != 0);
    if (lane == 0) maskU[(size_t)row * MASK_ULL + it * 4 + wave] = b;
  }
}

// ---------------------------------------------------------------- bf16 transpose (64x64 tiles)
template<int R, int C>
__global__ __launch_bounds__(256) void transpose_kernel(const bf16* __restrict__ src,
                                                        bf16* __restrict__ dst) {
  __shared__ bf16 t[64][72];
  int i0 = blockIdx.x * 64, j0 = blockIdx.y * 64;
  int rr = threadIdx.x >> 4;          // 0..15
  int cc = (threadIdx.x & 15) * 4;    // 0..60
#pragma unroll
  for (int p = 0; p < 4; ++p) {
    int r = p * 16 + rr;
    *(bf16x4*)&t[r][cc] = *(const bf16x4*)&src[(size_t)(i0 + r) * C + j0 + cc];
  }
  __syncthreads();
#pragma unroll
  for (int p = 0; p < 4; ++p) {
    int c = p * 16 + rr;
    bf16x4 v = { t[cc + 0][c], t[cc + 1][c], t[cc + 2][c], t[cc + 3][c] };
    *(bf16x4*)&dst[(size_t)(j0 + c) * R + i0 + cc] = v;
  }
}

// ---------------------------------------------------------------- sl/sr projections
template<int NHEADS, int NH>
__global__ __launch_bounds__(256) void head_proj_kernel(
    const bf16* __restrict__ g, int ldg,
    const float* __restrict__ a0, const float* __restrict__ a1, const float* __restrict__ a2,
    float* __restrict__ sl, float* __restrict__ sr) {
  int tid = blockIdx.x * 256 + threadIdx.x;
  int c = tid / N_NODES, i = tid - c * N_NODES;
  int b = c / NHEADS, h = c - b * NHEADS;
  const float* a = (b == 0) ? a0 : (b == 1) ? a1 : a2;
  const bf16* gr = g + (size_t)i * ldg + b * (NHEADS * NH) + h * NH;
  float accl = 0.f, accr = 0.f;
#pragma unroll 4
  for (int f = 0; f < NH; f += 4) {
    bf16x4 v = *(const bf16x4*)&gr[f];
#pragma unroll
    for (int k = 0; k < 4; ++k) {
      float gv = (float)v[k];
      accl += gv * a[f + k];
      accr += gv * a[NH + f + k];
    }
  }
  sl[c * N_NODES + i] = accl;
  sr[c * N_NODES + i] = accr;
}

// ---------------------------------------------------------------- column means (uniform-softmax fallback)
__global__ void colmean_kernel(const bf16* __restrict__ g, int C, float* __restrict__ out) {
  int c = blockIdx.x * blockDim.x + threadIdx.x;
  if (c >= C) return;
  float s = 0.f;
  for (int r = 0; r < N_NODES; ++r) s += (float)g[(size_t)r * C + c];
  out[c] = s * (1.0f / N_NODES);
}

// ---------------------------------------------------------------- GEMM: C = A(bf16) * B(bf16,[N][K])^T  (+bias, leaky, +res)
// 128x128 tile, BK=64, 4 waves (2x2 of 64x64), XOR-swizzled LDS, reg-staged.
template<bool BIAS, bool LEAKY, bool RES, bool F32OUT>
__global__ __launch_bounds__(256) void gemm_kernel(
    const bf16* __restrict__ A, int lda, int aZoff,
    const bf16* __restrict__ B0, const bf16* __restrict__ B1, const bf16* __restrict__ B2,
    int ldb, void* __restrict__ Cout, int ldc, int cZoff, int K,
    const float* __restrict__ bias, const float* __restrict__ res) {
  __shared__ bf16 As[128 * 64];
  __shared__ bf16 Bs[128 * 64];
  int z = blockIdx.z;
  const bf16* Ab = A + (size_t)z * aZoff;
  const bf16* Bb = (z == 0) ? B0 : (z == 1) ? B1 : B2;
  int m0 = blockIdx.x * 128, n0 = blockIdx.y * 128;
  int tid = threadIdx.x;
  int lane = tid & 63, wave = tid >> 6;
  int wm = wave >> 1, wn = wave & 1;
  int l15 = lane & 15, lk = lane >> 4;
  f32x4 acc[4][4] = {};
  for (int kt = 0; kt < K; kt += 64) {
#pragma unroll
    for (int it = 0; it < 4; ++it) {
      int unit = it * 256 + tid;
      int r = unit >> 3, up = unit & 7;
      int u = up ^ (r & 7);           // logical k-unit staged at swizzled slot up
      *(bf16x8*)&As[r * 64 + up * 8] = *(const bf16x8*)&Ab[(size_t)(m0 + r) * lda + kt + u * 8];
      *(bf16x8*)&Bs[r * 64 + up * 8] = *(const bf16x8*)&Bb[(size_t)(n0 + r) * ldb + kt + u * 8];
    }
    __syncthreads();
#pragma unroll
    for (int s = 0; s < 2; ++s) {
      bf16x8 af[4], bfr[4];
      int u = s * 4 + lk;
#pragma unroll
      for (int mi = 0; mi < 4; ++mi) {
        int r = wm * 64 + mi * 16 + l15;
        af[mi] = *(const bf16x8*)&As[r * 64 + (u ^ (r & 7)) * 8];
      }
#pragma unroll
      for (int ni = 0; ni < 4; ++ni) {
        int r = wn * 64 + ni * 16 + l15;
        bfr[ni] = *(const bf16x8*)&Bs[r * 64 + (u ^ (r & 7)) * 8];
      }
#pragma unroll
      for (int mi = 0; mi < 4; ++mi)
#pragma unroll
        for (int ni = 0; ni < 4; ++ni)
          acc[mi][ni] = __builtin_amdgcn_mfma_f32_16x16x32_bf16(af[mi], bfr[ni], acc[mi][ni], 0, 0, 0);
    }
    __syncthreads();
  }
#pragma unroll
  for (int mi = 0; mi < 4; ++mi)
#pragma unroll
    for (int ni = 0; ni < 4; ++ni)
#pragma unroll
      for (int r = 0; r < 4; ++r) {
        int i = m0 + wm * 64 + mi * 16 + lk * 4 + r;
        int col = z * cZoff + n0 + wn * 64 + ni * 16 + l15;
        float v = acc[mi][ni][r];
        if (BIAS) v += bias[col];
        if (LEAKY) v = (v >= 0.f) ? v : 0.01f * v;
        if (RES) v += res[(size_t)i * ldc + col];
        if (F32OUT) ((float*)Cout)[(size_t)i * ldc + col] = v;
        else        ((bf16*)Cout)[(size_t)i * ldc + col] = (bf16)v;
      }
}

// ---------------------------------------------------------------- P-tile build (8 j's per lane)
__device__ __forceinline__ void build_p(float sl, const float* __restrict__ srp,
                                        const unsigned char* __restrict__ mrow,
                                        int jb, int jlo, int jhi,
                                        bf16x8& a8, float& lsum) {
  unsigned int mb = mrow[jb >> 3];
  float4 s0 = *(const float4*)&srp[jb];
  float4 s1 = *(const float4*)&srp[jb + 4];
  float se[8] = { s0.x, s0.y, s0.z, s0.w, s1.x, s1.y, s1.z, s1.w };
#pragma unroll
  for (int e = 0; e < 8; ++e) {
    float x = sl + se[e];
    x = (x >= 0.f) ? x : 0.2f * x;          // LeakyReLU slope 0.2 (GAT)
    float p = __expf(x);
    int j = jb + e;
    bool valid = ((mb >> e) & 1u) && (j >= jlo) && (j < jhi);
    p = valid ? p : 0.f;
    bf16 pb = (bf16)p;
    a8[e] = pb;
    lsum += (float)pb;                      // denominator from the SAME rounded p
  }
}

// ---------------------------------------------------------------- attention layer 1 (18 combos, F=64) + ELU
__global__ __launch_bounds__(256) void att1_kernel(
    const bf16* __restrict__ gT, const float* __restrict__ slA, const float* __restrict__ srA,
    const unsigned char* __restrict__ maskB, const float* __restrict__ gmean,
    const int* __restrict__ dnum, const int* __restrict__ snum,
    bf16* __restrict__ out1) {
  int c = blockIdx.x;               // branch*6+head
  int b = c / HEADS;
  int wave = threadIdx.x >> 6, lane = threadIdx.x & 63;
  int l15 = lane & 15, lk = lane >> 4;
  int i0 = blockIdx.y * 64 + wave * 16;
  int dn = dnum[0], sn = snum[0];
  int bb1 = N_NODES - sn - dn, bb2 = N_NODES - dn;
  int jlo = (b == 0) ? 0 : (b == 1) ? bb1 : bb2;
  int jhi = (b == 0) ? bb1 : (b == 1) ? bb2 : N_NODES;
  int cbase = c * NH1;
  int ip = i0 + l15;
  float sl = slA[c * N_NODES + ip];
  const float* srp = srA + c * N_NODES;
  const unsigned char* mrow = maskB + (size_t)ip * MASK_BYTES;
  f32x4 acc[4] = {};
  float lsum = 0.f;
  for (int jt = (jlo & ~31); jt < jhi; jt += 32) {
    int jb = jt + lk * 8;
    bf16x8 a8;
    build_p(sl, srp, mrow, jb, jlo, jhi, a8, lsum);
#pragma unroll
    for (int nf = 0; nf < 4; ++nf) {
      bf16x8 b8 = *(const bf16x8*)&gT[(size_t)(cbase + nf * 16 + l15) * N_NODES + jb];
      acc[nf] = __builtin_amdgcn_mfma_f32_16x16x32_bf16(a8, b8, acc[nf], 0, 0, 0);
    }
  }
  lsum += __shfl_xor(lsum, 16, 64);
  lsum += __shfl_xor(lsum, 32, 64);
#pragma unroll
  for (int nf = 0; nf < 4; ++nf) {
    int f = cbase + nf * 16 + l15;
#pragma unroll
    for (int r = 0; r < 4; ++r) {
      int i = i0 + lk * 4 + r;
      float lr = __shfl(lsum, lk * 4 + r, 64);
      float v = (lr > 0.f) ? acc[nf][r] / lr : gmean[f];  // all-masked row -> uniform mean
      v = (v > 0.f) ? v : (__expf(v) - 1.f);              // ELU
      out1[(size_t)i * C1 + f] = (bf16)v;
    }
  }
}

// ---------------------------------------------------------------- attention layer 2 (3 combos, F=256) + residual, write fused
__global__ __launch_bounds__(256) void att2_kernel(
    const bf16* __restrict__ gT, const float* __restrict__ slA, const float* __restrict__ srA,
    const unsigned char* __restrict__ maskB, const float* __restrict__ gmean,
    const float* __restrict__ feat, const int* __restrict__ dnum, const int* __restrict__ snum,
    bf16* __restrict__ fused) {
  __shared__ float redA[2][64][64];
  __shared__ float redL[2][64];
  int b = blockIdx.x;               // branch
  int wave = threadIdx.x >> 6, lane = threadIdx.x & 63;
  int l15 = lane & 15, lk = lane >> 4;
  int mfr = wave & 1, par = wave >> 1;   // waves: (mfrag, j-parity)
  int i0 = blockIdx.y * 32 + mfr * 16;
  int dn = dnum[0], sn = snum[0];
  int bb1 = N_NODES - sn - dn, bb2 = N_NODES - dn;
  int jlo = (b == 0) ? 0 : (b == 1) ? bb1 : bb2;
  int jhi = (b == 0) ? bb1 : (b == 1) ? bb2 : N_NODES;
  int ip = i0 + l15;
  float sl = slA[b * N_NODES + ip];
  const float* srp = srA + b * N_NODES;
  const unsigned char* mrow = maskB + (size_t)ip * MASK_BYTES;
  f32x4 acc[16] = {};
  float lsum = 0.f;
  for (int jt = (jlo & ~31) + par * 32; jt < jhi; jt += 64) {
    int jb = jt + lk * 8;
    bf16x8 a8;
    build_p(sl, srp, mrow, jb, jlo, jhi, a8, lsum);
#pragma unroll
    for (int nf = 0; nf < 16; ++nf) {
      bf16x8 b8 = *(const bf16x8*)&gT[(size_t)(b * D_IN + nf * 16 + l15) * N_NODES + jb];
      acc[nf] = __builtin_amdgcn_mfma_f32_16x16x32_bf16(a8, b8, acc[nf], 0, 0, 0);
    }
  }
  if (par == 1) {
#pragma unroll
    for (int nf = 0; nf < 16; ++nf) *(f32x4*)&redA[mfr][lane][nf * 4] = acc[nf];
    redL[mfr][lane] = lsum;
  }
  __syncthreads();
  if (par == 0) {
#pragma unroll
    for (int nf = 0; nf < 16; ++nf) {
      f32x4 o = *(const f32x4*)&redA[mfr][lane][nf * 4];
      acc[nf] += o;
    }
    lsum += redL[mfr][lane];
    lsum += __shfl_xor(lsum, 16, 64);
    lsum += __shfl_xor(lsum, 32, 64);
    int fo = (2 - b) * D_IN;    // concat order: [doc, sect, sent]
#pragma unroll
    for (int nf = 0; nf < 16; ++nf) {
      int f = nf * 16 + l15;
#pragma unroll
      for (int r = 0; r < 4; ++r) {
        int i = i0 + lk * 4 + r;
        float lr = __shfl(lsum, lk * 4 + r, 64);
        float v = (lr > 0.f) ? acc[nf][r] / lr : gmean[b * D_IN + f];
        v += feat[(size_t)i * D_IN + f];     // + f residual
        fused[(size_t)i * C2 + fo + f] = (bf16)v;
      }
    }
  }
}

// ---------------------------------------------------------------- launch
extern "C" void kernel_launch(void* const* d_in, const int* in_sizes, int n_in,
                              void* d_out, int out_size, void* d_ws, size_t ws_size,
                              hipStream_t stream) {
  (void)in_sizes; (void)n_in; (void)out_size; (void)ws_size;
  const float* feature = (const float*)d_in[0];
  const int*   adj     = (const int*)d_in[1];
  const int*   dnum    = (const int*)d_in[2];
  const int*   snum    = (const int*)d_in[3];
  const float* W1s = (const float*)d_in[4];  const float* a1s = (const float*)d_in[5];
  const float* W2s = (const float*)d_in[6];  const float* a2s = (const float*)d_in[7];
  const float* W1e = (const float*)d_in[8];  const float* a1e = (const float*)d_in[9];
  const float* W2e = (const float*)d_in[10]; const float* a2e = (const float*)d_in[11];
  const float* W1d = (const float*)d_in[12]; const float* a1d = (const float*)d_in[13];
  const float* W2d = (const float*)d_in[14]; const float* a2d = (const float*)d_in[15];
  const float* fW  = (const float*)d_in[16]; const float* fB  = (const float*)d_in[17];
  const float* w0  = (const float*)d_in[18]; const float* b0  = (const float*)d_in[19];
  const float* w1  = (const float*)d_in[20]; const float* b1  = (const float*)d_in[21];
  const float* w2  = (const float*)d_in[22]; const float* b2  = (const float*)d_in[23];

  char* ws = (char*)d_ws;
  size_t off = 0;
  auto alloc = [&](size_t bytes) { void* p = ws + off; off += (bytes + 255) & ~(size_t)255; return p; };

  unsigned long long* maskU = (unsigned long long*)alloc((size_t)N_NODES * MASK_ULL * 8);
  bf16* fbf   = (bf16*)alloc((size_t)N_NODES * D_IN * 2);
  bf16* w1b0  = (bf16*)alloc(HIDDEN * D_IN * 2);
  bf16* w1b1  = (bf16*)alloc(HIDDEN * D_IN * 2);
  bf16* w1b2  = (bf16*)alloc(HIDDEN * D_IN * 2);
  bf16* w2b0  = (bf16*)alloc(D_IN * HIDDEN * 2);
  bf16* w2b1  = (bf16*)alloc(D_IN * HIDDEN * 2);
  bf16* w2b2  = (bf16*)alloc(D_IN * HIDDEN * 2);
  bf16* wfusb = (bf16*)alloc(D_IN * C2 * 2);
  bf16* wf0b  = (bf16*)alloc(HIDDEN * D_IN * 2);
  bf16* wf1b  = (bf16*)alloc(HIDDEN * HIDDEN * 2);
  bf16* wf2b  = (bf16*)alloc(D_IN * HIDDEN * 2);
  bf16* g1    = (bf16*)alloc((size_t)N_NODES * C1 * 2);
  bf16* g1T   = (bf16*)alloc((size_t)N_NODES * C1 * 2);
  bf16* out1  = (bf16*)alloc((size_t)N_NODES * C1 * 2);
  bf16* g2    = (bf16*)alloc((size_t)N_NODES * C2 * 2);
  bf16* g2T   = (bf16*)alloc((size_t)N_NODES * C2 * 2);
  bf16* fusedB= (bf16*)alloc((size_t)N_NODES * C2 * 2);
  bf16* h0    = (bf16*)alloc((size_t)N_NODES * D_IN * 2);
  bf16* h1    = (bf16*)alloc((size_t)N_NODES * HIDDEN * 2);
  bf16* h2    = (bf16*)alloc((size_t)N_NODES * HIDDEN * 2);
  float* sl1  = (float*)alloc(18 * N_NODES * 4);
  float* sr1  = (float*)alloc(18 * N_NODES * 4);
  float* sl2  = (float*)alloc(3 * N_NODES * 4);
  float* sr2  = (float*)alloc(3 * N_NODES * 4);
  float* gm1  = (float*)alloc(C1 * 4);
  float* gm2  = (float*)alloc(C2 * 4);
  const unsigned char* maskBytes = (const unsigned char*)maskU;

  // 1) casts
  CastArgs ca;
  {
    const float* srcs[11] = { feature, W1s, W1e, W1d, W2s, W2e, W2d, fW, w0, w1, w2 };
    bf16* dsts[11] = { fbf, w1b0, w1b1, w1b2, w2b0, w2b1, w2b2, wfusb, wf0b, wf1b, wf2b };
    int counts[11] = { N_NODES*D_IN, HIDDEN*D_IN, HIDDEN*D_IN, HIDDEN*D_IN,
                       D_IN*HIDDEN, D_IN*HIDDEN, D_IN*HIDDEN, D_IN*C2,
                       HIDDEN*D_IN, HIDDEN*HIDDEN, D_IN*HIDDEN };
    int cum = 0;
    for (int k = 0; k < 11; ++k) { ca.src[k] = srcs[k]; ca.dst[k] = dsts[k]; ca.cum4[k] = cum; cum += counts[k] / 4; }
    ca.cum4[11] = cum;
    cast_all_kernel<<<cum / 256, 256, 0, stream>>>(ca);
  }
  // 2) pack adjacency bits
  pack_adj_kernel<<<N_NODES, 256, 0, stream>>>(adj, maskU);
  // 3) g1 = f @ W1^T (3 branches via z)
  gemm_kernel<false,false,false,false><<<dim3(24,3,3), 256, 0, stream>>>(
      fbf, D_IN, 0, w1b0, w1b1, w1b2, D_IN, g1, C1, HIDDEN, D_IN, nullptr, nullptr);
  // 4) transpose g1
  transpose_kernel<N_NODES, C1><<<dim3(48,18), 256, 0, stream>>>(g1, g1T);
  // 5) sl/sr layer1
  head_proj_kernel<HEADS, NH1><<<18 * N_NODES / 256, 256, 0, stream>>>(g1, C1, a1s, a1e, a1d, sl1, sr1);
  // 6) colmean g1
  colmean_kernel<<<(C1 + 255) / 256, 256, 0, stream>>>(g1, C1, gm1);
  // 7) attention 1 (+ELU)
  att1_kernel<<<dim3(18,48), 256, 0, stream>>>(g1T, sl1, sr1, maskBytes, gm1, dnum, snum, out1);
  // 8) g2 = elu(out1) @ W2^T per branch
  gemm_kernel<false,false,false,false><<<dim3(24,2,3), 256, 0, stream>>>(
      out1, C1, HIDDEN, w2b0, w2b1, w2b2, HIDDEN, g2, C2, D_IN, HIDDEN, nullptr, nullptr);
  // 9) transpose g2
  transpose_kernel<N_NODES, C2><<<dim3(48,12), 256, 0, stream>>>(g2, g2T);
  // 10) sl/sr layer2
  head_proj_kernel<1, D_IN><<<3 * N_NODES / 256, 256, 0, stream>>>(g2, C2, a2s, a2e, a2d, sl2, sr2);
  // 11) colmean g2
  colmean_kernel<<<(C2 + 255) / 256, 256, 0, stream>>>(g2, C2, gm2);
  // 12) attention 2 (+residual, writes fused [doc,sect,sent])
  att2_kernel<<<dim3(3,96), 256, 0, stream>>>(g2T, sl2, sr2, maskBytes, gm2, feature, dnum, snum, fusedB);
  // 13) fusion: h0 = leaky(fused @ fW^T + fB)
  gemm_kernel<true,true,false,false><<<dim3(24,2,1), 256, 0, stream>>>(
      fusedB, C2, 0, wfusb, wfusb, wfusb, C2, h0, D_IN, 0, C2, fB, nullptr);
  // 14) ffn0: h1 = leaky(h0 @ w0^T + b0)
  gemm_kernel<true,true,false,false><<<dim3(24,3,1), 256, 0, stream>>>(
      h0, D_IN, 0, wf0b, wf0b, wf0b, D_IN, h1, HIDDEN, 0, D_IN, b0, nullptr);
  // 15) ffn1: h2 = leaky(h1 @ w1^T + b1)
  gemm_kernel<true,true,false,false><<<dim3(24,3,1), 256, 0, stream>>>(
      h1, HIDDEN, 0, wf1b, wf1b, wf1b, HIDDEN, h2, HIDDEN, 0, HIDDEN, b1, nullptr);
  // 16) ffn2: out = leaky(h2 @ w2^T + b2) + f   (fp32 out)
  gemm_kernel<true,true,true,true><<<dim3(24,2,1), 256, 0, stream>>>(
      h2, HIDDEN, 0, wf2b, wf2b, wf2b, HIDDEN, d_out, D_IN, 0, HIDDEN, b2, feature);
}

// Round 2
// 411.847 us; speedup vs baseline: 2.1385x; 2.1385x over previous
//
#include <hip/hip_runtime.h>
#include <stdint.h>

#define N_NODES 3072
#define D_IN    256
#define HIDDEN  384
#define HEADS   6
#define NH1     64
#define C1      1152   // 3*HIDDEN
#define C2      768    // 3*D_IN
#define MASK_ULL   48  // 3072/64 per row
#define MASK_BYTES 384 // 3072/8 per row
#define S1      4      // j-splits for att1
#define S2      8      // j-splits for att2

typedef __bf16 bf16;
typedef __bf16 bf16x8 __attribute__((ext_vector_type(8)));
typedef __bf16 bf16x4 __attribute__((ext_vector_type(4)));
typedef float  f32x4  __attribute__((ext_vector_type(4)));

__device__ __forceinline__ void atomAddF(float* p, float v) {
  __hip_atomic_fetch_add(p, v, __ATOMIC_RELAXED, __HIP_MEMORY_SCOPE_AGENT);
}

// ---------------------------------------------------------------- cast fp32->bf16
struct CastArgs {
  const float* src[11];
  bf16*        dst[11];
  int          cum4[12];
};

__global__ __launch_bounds__(256) void cast_all_kernel(CastArgs A) {
  int g = blockIdx.x * 256 + threadIdx.x;
  int j = 0;
#pragma unroll
  for (int k = 1; k < 11; ++k) j += (g >= A.cum4[k]);
  int e = (g - A.cum4[j]) * 4;
  float4 v = *(const float4*)(A.src[j] + e);
  bf16x4 o = { (bf16)v.x, (bf16)v.y, (bf16)v.z, (bf16)v.w };
  *(bf16x4*)(A.dst[j] + e) = o;
}

// ---------------------------------------------------------------- adj -> bitmask
__global__ __launch_bounds__(256) void pack_adj_kernel(const int* __restrict__ adj,
                                                       unsigned long long* __restrict__ maskU) {
  int row = blockIdx.x;
  const int* ar = adj + (size_t)row * N_NODES;
  int lane = threadIdx.x & 63, wave = threadIdx.x >> 6;
#pragma unroll
  for (int it = 0; it < N_NODES / 256; ++it) {
    int j = it * 256 + wave * 64 + lane;
    unsigned long long b = __ballot(ar[j] != 0);
    if (lane == 0) maskU[(size_t)row * MASK_ULL + it * 4 + wave] = b;
  }
}

// ---------------------------------------------------------------- pack g[j][f] -> gP[j/8][f][8]  (coalesced MFMA B-frags)
template<int C>
__global__ __launch_bounds__(256) void pack_kernel(const bf16* __restrict__ src,
                                                   bf16* __restrict__ dst) {
  __shared__ bf16 t[64][72];
  int j0 = blockIdx.x * 64, f0 = blockIdx.y * 64;
  int rr = threadIdx.x >> 4;          // 0..15
  int cc = (threadIdx.x & 15) * 4;    // 0..60
#pragma unroll
  for (int p = 0; p < 4; ++p) {
    int r = p * 16 + rr;
    *(bf16x4*)&t[r][cc] = *(const bf16x4*)&src[(size_t)(j0 + r) * C + f0 + cc];
  }
  __syncthreads();
  int f = threadIdx.x & 63, g = threadIdx.x >> 6;   // g = 0..3
#pragma unroll
  for (int q = 0; q < 2; ++q) {
    int p = g * 2 + q;                               // panel 0..7 within tile
    bf16x8 v = { t[p*8+0][f], t[p*8+1][f], t[p*8+2][f], t[p*8+3][f],
                 t[p*8+4][f], t[p*8+5][f], t[p*8+6][f], t[p*8+7][f] };
    *(bf16x8*)&dst[ ((size_t)((j0 >> 3) + p) * C + f0 + f) * 8 ] = v;
  }
}

// ---------------------------------------------------------------- sl/sr projections
template<int NHEADS, int NH>
__global__ __launch_bounds__(256) void head_proj_kernel(
    const bf16* __restrict__ g, int ldg,
    const float* __restrict__ a0, const float* __restrict__ a1, const float* __restrict__ a2,
    float* __restrict__ sl, float* __restrict__ sr) {
  int tid = blockIdx.x * 256 + threadIdx.x;
  int c = tid / N_NODES, i = tid - c * N_NODES;
  int b = c / NHEADS, h = c - b * NHEADS;
  const float* a = (b == 0) ? a0 : (b == 1) ? a1 : a2;
  const bf16* gr = g + (size_t)i * ldg + b * (NHEADS * NH) + h * NH;
  float accl = 0.f, accr = 0.f;
#pragma unroll 4
  for (int f = 0; f < NH; f += 4) {
    bf16x4 v = *(const bf16x4*)&gr[f];
#pragma unroll
    for (int k = 0; k < 4; ++k) {
      float gv = (float)v[k];
      accl += gv * a[f + k];
      accr += gv * a[NH + f + k];
    }
  }
  sl[c * N_NODES + i] = accl;
  sr[c * N_NODES + i] = accr;
}

// ---------------------------------------------------------------- column means (uniform-softmax fallback)
__global__ __launch_bounds__(256) void colmean_kernel(const bf16* __restrict__ g, int C,
                                                      float* __restrict__ out) {
  int c = blockIdx.x * 256 + threadIdx.x;
  if (c >= C) return;
  int r0 = blockIdx.y * 128;
  float s = 0.f;
  for (int r = r0; r < r0 + 128; ++r) s += (float)g[(size_t)r * C + c];
  atomAddF(&out[c], s * (1.0f / N_NODES));
}

// ---------------------------------------------------------------- GEMM: C = A(bf16) * B(bf16,[N][K])^T  (+bias, leaky, +res)
template<bool BIAS, bool LEAKY, bool RES, bool F32OUT>
__global__ __launch_bounds__(256) void gemm_kernel(
    const bf16* __restrict__ A, int lda, int aZoff,
    const bf16* __restrict__ B0, const bf16* __restrict__ B1, const bf16* __restrict__ B2,
    int ldb, void* __restrict__ Cout, int ldc, int cZoff, int K,
    const float* __restrict__ bias, const float* __restrict__ res) {
  __shared__ bf16 As[128 * 64];
  __shared__ bf16 Bs[128 * 64];
  int z = blockIdx.z;
  const bf16* Ab = A + (size_t)z * aZoff;
  const bf16* Bb = (z == 0) ? B0 : (z == 1) ? B1 : B2;
  int m0 = blockIdx.x * 128, n0 = blockIdx.y * 128;
  int tid = threadIdx.x;
  int lane = tid & 63, wave = tid >> 6;
  int wm = wave >> 1, wn = wave & 1;
  int l15 = lane & 15, lk = lane >> 4;
  f32x4 acc[4][4] = {};
  for (int kt = 0; kt < K; kt += 64) {
#pragma unroll
    for (int it = 0; it < 4; ++it) {
      int unit = it * 256 + tid;
      int r = unit >> 3, up = unit & 7;
      int u = up ^ (r & 7);
      *(bf16x8*)&As[r * 64 + up * 8] = *(const bf16x8*)&Ab[(size_t)(m0 + r) * lda + kt + u * 8];
      *(bf16x8*)&Bs[r * 64 + up * 8] = *(const bf16x8*)&Bb[(size_t)(n0 + r) * ldb + kt + u * 8];
    }
    __syncthreads();
#pragma unroll
    for (int s = 0; s < 2; ++s) {
      bf16x8 af[4], bfr[4];
      int u = s * 4 + lk;
#pragma unroll
      for (int mi = 0; mi < 4; ++mi) {
        int r = wm * 64 + mi * 16 + l15;
        af[mi] = *(const bf16x8*)&As[r * 64 + (u ^ (r & 7)) * 8];
      }
#pragma unroll
      for (int ni = 0; ni < 4; ++ni) {
        int r = wn * 64 + ni * 16 + l15;
        bfr[ni] = *(const bf16x8*)&Bs[r * 64 + (u ^ (r & 7)) * 8];
      }
#pragma unroll
      for (int mi = 0; mi < 4; ++mi)
#pragma unroll
        for (int ni = 0; ni < 4; ++ni)
          acc[mi][ni] = __builtin_amdgcn_mfma_f32_16x16x32_bf16(af[mi], bfr[ni], acc[mi][ni], 0, 0, 0);
    }
    __syncthreads();
  }
#pragma unroll
  for (int mi = 0; mi < 4; ++mi)
#pragma unroll
    for (int ni = 0; ni < 4; ++ni)
#pragma unroll
      for (int r = 0; r < 4; ++r) {
        int i = m0 + wm * 64 + mi * 16 + lk * 4 + r;
        int col = z * cZoff + n0 + wn * 64 + ni * 16 + l15;
        float v = acc[mi][ni][r];
        if (BIAS) v += bias[col];
        if (LEAKY) v = (v >= 0.f) ? v : 0.01f * v;
        if (RES) v += res[(size_t)i * ldc + col];
        if (F32OUT) ((float*)Cout)[(size_t)i * ldc + col] = v;
        else        ((bf16*)Cout)[(size_t)i * ldc + col] = (bf16)v;
      }
}

// ---------------------------------------------------------------- P-tile build (8 j's per lane)
__device__ __forceinline__ void build_p(float sl, const float* __restrict__ srp,
                                        const unsigned char* __restrict__ mrow,
                                        int jb, int jlo, int jhi,
                                        bf16x8& a8, float& lsum) {
  unsigned int mb = mrow[jb >> 3];
  float4 s0 = *(const float4*)&srp[jb];
  float4 s1 = *(const float4*)&srp[jb + 4];
  float se[8] = { s0.x, s0.y, s0.z, s0.w, s1.x, s1.y, s1.z, s1.w };
#pragma unroll
  for (int e = 0; e < 8; ++e) {
    float x = sl + se[e];
    x = (x >= 0.f) ? x : 0.2f * x;          // LeakyReLU slope 0.2 (GAT)
    float p = __expf(x);
    int j = jb + e;
    bool valid = ((mb >> e) & 1u) && (j >= jlo) && (j < jhi);
    p = valid ? p : 0.f;
    bf16 pb = (bf16)p;
    a8[e] = pb;
    lsum += (float)pb;
  }
}

// ---------------------------------------------------------------- attention layer 1: partial (acc,l) over j-split, atomic accumulate
__global__ __launch_bounds__(256) void att1_kernel(
    const bf16* __restrict__ gP, const float* __restrict__ slA, const float* __restrict__ srA,
    const unsigned char* __restrict__ maskB,
    const int* __restrict__ dnum, const int* __restrict__ snum,
    float* __restrict__ acc1, float* __restrict__ l1) {
  int c = blockIdx.x;               // branch*6+head
  int b = c / HEADS;
  int wave = threadIdx.x >> 6, lane = threadIdx.x & 63;
  int l15 = lane & 15, lk = lane >> 4;
  int i0 = blockIdx.y * 64 + wave * 16;
  int dn = dnum[0], sn = snum[0];
  int bb1 = N_NODES - sn - dn, bb2 = N_NODES - dn;
  int jlo = (b == 0) ? 0 : (b == 1) ? bb1 : bb2;
  int jhi = (b == 0) ? bb1 : (b == 1) ? bb2 : N_NODES;
  int len = jhi - jlo, s = blockIdx.z;
  int slo = jlo + (len * s) / S1, shi = jlo + (len * (s + 1)) / S1;
  if (slo >= shi) return;
  int cbase = c * NH1;
  int ip = i0 + l15;
  float sl = slA[c * N_NODES + ip];
  const float* srp = srA + c * N_NODES;
  const unsigned char* mrow = maskB + (size_t)ip * MASK_BYTES;
  f32x4 acc[4] = {};
  float lsum = 0.f;
  for (int jt = (slo & ~31); jt < shi; jt += 32) {
    int jb = jt + lk * 8;
    bf16x8 a8;
    build_p(sl, srp, mrow, jb, slo, shi, a8, lsum);
    size_t pbase = (size_t)(jb >> 3) * C1 * 8;
#pragma unroll
    for (int nf = 0; nf < 4; ++nf) {
      bf16x8 b8 = *(const bf16x8*)&gP[pbase + (size_t)(cbase + nf * 16 + l15) * 8];
      acc[nf] = __builtin_amdgcn_mfma_f32_16x16x32_bf16(a8, b8, acc[nf], 0, 0, 0);
    }
  }
  lsum += __shfl_xor(lsum, 16, 64);
  lsum += __shfl_xor(lsum, 32, 64);
  if (lane < 16) atomAddF(&l1[c * N_NODES + i0 + lane], lsum);
#pragma unroll
  for (int nf = 0; nf < 4; ++nf)
#pragma unroll
    for (int r = 0; r < 4; ++r)
      atomAddF(&acc1[(size_t)(i0 + lk * 4 + r) * C1 + cbase + nf * 16 + l15], acc[nf][r]);
}

// ---------------------------------------------------------------- finalize layer 1: /l (or gmean) + ELU -> bf16
__global__ __launch_bounds__(256) void fin1_kernel(
    const float* __restrict__ acc1, const float* __restrict__ l1,
    const float* __restrict__ gm, bf16* __restrict__ out1) {
  int t = blockIdx.x * 256 + threadIdx.x;      // one thread = 8 cols
  int i = t / (C1 / 8), f0 = (t % (C1 / 8)) * 8;
  int c = f0 >> 6;
  float l = l1[c * N_NODES + i];
  float inv = (l > 0.f) ? 1.f / l : 0.f;
  bf16x8 o;
#pragma unroll
  for (int e = 0; e < 8; ++e) {
    float v = (l > 0.f) ? acc1[(size_t)i * C1 + f0 + e] * inv : gm[f0 + e];
    v = (v > 0.f) ? v : (__expf(v) - 1.f);     // ELU
    o[e] = (bf16)v;
  }
  *(bf16x8*)&out1[(size_t)i * C1 + f0] = o;
}

// ---------------------------------------------------------------- attention layer 2: partial (acc,l), atomic accumulate
__global__ __launch_bounds__(256) void att2_kernel(
    const bf16* __restrict__ gP, const float* __restrict__ slA, const float* __restrict__ srA,
    const unsigned char* __restrict__ maskB,
    const int* __restrict__ dnum, const int* __restrict__ snum,
    float* __restrict__ acc2, float* __restrict__ l2) {
  int b = blockIdx.x;               // branch
  int wave = threadIdx.x >> 6, lane = threadIdx.x & 63;
  int l15 = lane & 15, lk = lane >> 4;
  int i0 = blockIdx.y * 64 + wave * 16;
  int dn = dnum[0], sn = snum[0];
  int bb1 = N_NODES - sn - dn, bb2 = N_NODES - dn;
  int jlo = (b == 0) ? 0 : (b == 1) ? bb1 : bb2;
  int jhi = (b == 0) ? bb1 : (b == 1) ? bb2 : N_NODES;
  int len = jhi - jlo, s = blockIdx.z;
  int slo = jlo + (len * s) / S2, shi = jlo + (len * (s + 1)) / S2;
  if (slo >= shi) return;
  int ip = i0 + l15;
  float sl = slA[b * N_NODES + ip];
  const float* srp = srA + b * N_NODES;
  const unsigned char* mrow = maskB + (size_t)ip * MASK_BYTES;
  f32x4 acc[16] = {};
  float lsum = 0.f;
  for (int jt = (slo & ~31); jt < shi; jt += 32) {
    int jb = jt + lk * 8;
    bf16x8 a8;
    build_p(sl, srp, mrow, jb, slo, shi, a8, lsum);
    size_t pbase = (size_t)(jb >> 3) * C2 * 8;
#pragma unroll
    for (int nf = 0; nf < 16; ++nf) {
      bf16x8 b8 = *(const bf16x8*)&gP[pbase + (size_t)(b * D_IN + nf * 16 + l15) * 8];
      acc[nf] = __builtin_amdgcn_mfma_f32_16x16x32_bf16(a8, b8, acc[nf], 0, 0, 0);
    }
  }
  lsum += __shfl_xor(lsum, 16, 64);
  lsum += __shfl_xor(lsum, 32, 64);
  if (lane < 16) atomAddF(&l2[b * N_NODES + i0 + lane], lsum);
#pragma unroll
  for (int nf = 0; nf < 16; ++nf)
#pragma unroll
    for (int r = 0; r < 4; ++r)
      atomAddF(&acc2[(size_t)(i0 + lk * 4 + r) * C2 + b * D_IN + nf * 16 + l15], acc[nf][r]);
}

// ---------------------------------------------------------------- finalize layer 2: /l (or gmean) + residual -> fused [doc,sect,sent]
__global__ __launch_bounds__(256) void fin2_kernel(
    const float* __restrict__ acc2, const float* __restrict__ l2,
    const float* __restrict__ gm, const float* __restrict__ feat,
    bf16* __restrict__ fused) {
  int t = blockIdx.x * 256 + threadIdx.x;      // one thread = 8 cols
  int i = t / (C2 / 8), f0 = (t % (C2 / 8)) * 8;
  int b = f0 >> 8;                             // branch
  int fi = f0 & 255;                           // feature within branch
  int fo = (2 - b) * D_IN + fi;                // concat order: [doc, sect, sent]
  float l = l2[b * N_NODES + i];
  float inv = (l > 0.f) ? 1.f / l : 0.f;
  bf16x8 o;
#pragma unroll
  for (int e = 0; e < 8; ++e) {
    float v = (l > 0.f) ? acc2[(size_t)i * C2 + f0 + e] * inv : gm[f0 + e];
    v += feat[(size_t)i * D_IN + fi + e];
    o[e] = (bf16)v;
  }
  *(bf16x8*)&fused[(size_t)i * C2 + fo] = o;
}

// ---------------------------------------------------------------- launch
extern "C" void kernel_launch(void* const* d_in, const int* in_sizes, int n_in,
                              void* d_out, int out_size, void* d_ws, size_t ws_size,
                              hipStream_t stream) {
  (void)in_sizes; (void)n_in; (void)out_size; (void)ws_size;
  const float* feature = (const float*)d_in[0];
  const int*   adj     = (const int*)d_in[1];
  const int*   dnum    = (const int*)d_in[2];
  const int*   snum    = (const int*)d_in[3];
  const float* W1s = (const float*)d_in[4];  const float* a1s = (const float*)d_in[5];
  const float* W2s = (const float*)d_in[6];  const float* a2s = (const float*)d_in[7];
  const float* W1e = (const float*)d_in[8];  const float* a1e = (const float*)d_in[9];
  const float* W2e = (const float*)d_in[10]; const float* a2e = (const float*)d_in[11];
  const float* W1d = (const float*)d_in[12]; const float* a1d = (const float*)d_in[13];
  const float* W2d = (const float*)d_in[14]; const float* a2d = (const float*)d_in[15];
  const float* fW  = (const float*)d_in[16]; const float* fB  = (const float*)d_in[17];
  const float* w0  = (const float*)d_in[18]; const float* b0  = (const float*)d_in[19];
  const float* w1  = (const float*)d_in[20]; const float* b1  = (const float*)d_in[21];
  const float* w2  = (const float*)d_in[22]; const float* b2  = (const float*)d_in[23];

  char* ws = (char*)d_ws;
  size_t off = 0;
  auto alloc = [&](size_t bytes) { void* p = ws + off; off += (bytes + 255) & ~(size_t)255; return p; };

  unsigned long long* maskU = (unsigned long long*)alloc((size_t)N_NODES * MASK_ULL * 8);
  bf16* fbf   = (bf16*)alloc((size_t)N_NODES * D_IN * 2);
  bf16* w1b0  = (bf16*)alloc(HIDDEN * D_IN * 2);
  bf16* w1b1  = (bf16*)alloc(HIDDEN * D_IN * 2);
  bf16* w1b2  = (bf16*)alloc(HIDDEN * D_IN * 2);
  bf16* w2b0  = (bf16*)alloc(D_IN * HIDDEN * 2);
  bf16* w2b1  = (bf16*)alloc(D_IN * HIDDEN * 2);
  bf16* w2b2  = (bf16*)alloc(D_IN * HIDDEN * 2);
  bf16* wfusb = (bf16*)alloc(D_IN * C2 * 2);
  bf16* wf0b  = (bf16*)alloc(HIDDEN * D_IN * 2);
  bf16* wf1b  = (bf16*)alloc(HIDDEN * HIDDEN * 2);
  bf16* wf2b  = (bf16*)alloc(D_IN * HIDDEN * 2);
  bf16* g1    = (bf16*)alloc((size_t)N_NODES * C1 * 2);
  bf16* gP1   = (bf16*)alloc((size_t)N_NODES * C1 * 2);
  bf16* out1  = (bf16*)alloc((size_t)N_NODES * C1 * 2);
  bf16* g2    = (bf16*)alloc((size_t)N_NODES * C2 * 2);
  bf16* gP2   = (bf16*)alloc((size_t)N_NODES * C2 * 2);
  bf16* fusedB= (bf16*)alloc((size_t)N_NODES * C2 * 2);
  bf16* h0    = (bf16*)alloc((size_t)N_NODES * D_IN * 2);
  bf16* h1    = (bf16*)alloc((size_t)N_NODES * HIDDEN * 2);
  bf16* h2    = (bf16*)alloc((size_t)N_NODES * HIDDEN * 2);
  float* sl1  = (float*)alloc(18 * N_NODES * 4);
  float* sr1  = (float*)alloc(18 * N_NODES * 4);
  float* sl2  = (float*)alloc(3 * N_NODES * 4);
  float* sr2  = (float*)alloc(3 * N_NODES * 4);
  // zero-initialized region (single memset): accumulators + denominators + colmeans
  size_t zoff = off;
  float* acc1 = (float*)alloc((size_t)N_NODES * C1 * 4);
  float* acc2 = (float*)alloc((size_t)N_NODES * C2 * 4);
  float* l1   = (float*)alloc(18 * N_NODES * 4);
  float* l2   = (float*)alloc(3 * N_NODES * 4);
  float* gm1  = (float*)alloc(C1 * 4);
  float* gm2  = (float*)alloc(C2 * 4);
  size_t zbytes = off - zoff;
  const unsigned char* maskBytes = (const unsigned char*)maskU;

  hipMemsetAsync(ws + zoff, 0, zbytes, stream);

  // 1) casts
  CastArgs ca;
  {
    const float* srcs[11] = { feature, W1s, W1e, W1d, W2s, W2e, W2d, fW, w0, w1, w2 };
    bf16* dsts[11] = { fbf, w1b0, w1b1, w1b2, w2b0, w2b1, w2b2, wfusb, wf0b, wf1b, wf2b };
    int counts[11] = { N_NODES*D_IN, HIDDEN*D_IN, HIDDEN*D_IN, HIDDEN*D_IN,
                       D_IN*HIDDEN, D_IN*HIDDEN, D_IN*HIDDEN, D_IN*C2,
                       HIDDEN*D_IN, HIDDEN*HIDDEN, D_IN*HIDDEN };
    int cum = 0;
    for (int k = 0; k < 11; ++k) { ca.src[k] = srcs[k]; ca.dst[k] = dsts[k]; ca.cum4[k] = cum; cum += counts[k] / 4; }
    ca.cum4[11] = cum;
    cast_all_kernel<<<cum / 256, 256, 0, stream>>>(ca);
  }
  // 2) pack adjacency bits
  pack_adj_kernel<<<N_NODES, 256, 0, stream>>>(adj, maskU);
  // 3) g1 = f @ W1^T (3 branches via z)
  gemm_kernel<false,false,false,false><<<dim3(24,3,3), 256, 0, stream>>>(
      fbf, D_IN, 0, w1b0, w1b1, w1b2, D_IN, g1, C1, HIDDEN, D_IN, nullptr, nullptr);
  // 4) pack g1 -> gP1
  pack_kernel<C1><<<dim3(48,18), 256, 0, stream>>>(g1, gP1);
  // 5) sl/sr layer1
  head_proj_kernel<HEADS, NH1><<<18 * N_NODES / 256, 256, 0, stream>>>(g1, C1, a1s, a1e, a1d, sl1, sr1);
  // 6) colmean g1
  colmean_kernel<<<dim3((C1 + 255) / 256, 24), 256, 0, stream>>>(g1, C1, gm1);
  // 7) attention 1 (split-j partials, atomic)
  att1_kernel<<<dim3(18, 48, S1), 256, 0, stream>>>(gP1, sl1, sr1, maskBytes, dnum, snum, acc1, l1);
  // 7b) finalize 1 (+ELU)
  fin1_kernel<<<N_NODES * (C1 / 8) / 256, 256, 0, stream>>>(acc1, l1, gm1, out1);
  // 8) g2 = out1 @ W2^T per branch
  gemm_kernel<false,false,false,false><<<dim3(24,2,3), 256, 0, stream>>>(
      out1, C1, HIDDEN, w2b0, w2b1, w2b2, HIDDEN, g2, C2, D_IN, HIDDEN, nullptr, nullptr);
  // 9) pack g2 -> gP2
  pack_kernel<C2><<<dim3(48,12), 256, 0, stream>>>(g2, gP2);
  // 10) sl/sr layer2
  head_proj_kernel<1, D_IN><<<3 * N_NODES / 256, 256, 0, stream>>>(g2, C2, a2s, a2e, a2d, sl2, sr2);
  // 11) colmean g2
  colmean_kernel<<<dim3((C2 + 255) / 256, 24), 256, 0, stream>>>(g2, C2, gm2);
  // 12) attention 2 (split-j partials, atomic)
  att2_kernel<<<dim3(3, 48, S2), 256, 0, stream>>>(gP2, sl2, sr2, maskBytes, dnum, snum, acc2, l2);
  // 12b) finalize 2 (+residual, writes fused [doc,sect,sent])
  fin2_kernel<<<N_NODES * (C2 / 8) / 256, 256, 0, stream>>>(acc2, l2, gm2, feature, fusedB);
  // 13) fusion: h0 = leaky(fused @ fW^T + fB)
  gemm_kernel<true,true,false,false><<<dim3(24,2,1), 256, 0, stream>>>(
      fusedB, C2, 0, wfusb, wfusb, wfusb, C2, h0, D_IN, 0, C2, fB, nullptr);
  // 14) ffn0: h1 = leaky(h0 @ w0^T + b0)
  gemm_kernel<true,true,false,false><<<dim3(24,3,1), 256, 0, stream>>>(
      h0, D_IN, 0, wf0b, wf0b, wf0b, D_IN, h1, HIDDEN, 0, D_IN, b0, nullptr);
  // 15) ffn1: h2 = leaky(h1 @ w1^T + b1)
  gemm_kernel<true,true,false,false><<<dim3(24,3,1), 256, 0, stream>>>(
      h1, HIDDEN, 0, wf1b, wf1b, wf1b, HIDDEN, h2, HIDDEN, 0, HIDDEN, b1, nullptr);
  // 16) ffn2: out = leaky(h2 @ w2^T + b2) + f   (fp32 out)
  gemm_kernel<true,true,true,true><<<dim3(24,2,1), 256, 0, stream>>>(
      h2, HIDDEN, 0, wf2b, wf2b, wf2b, HIDDEN, d_out, D_IN, 0, HIDDEN, b2, feature);
}

// Round 3
// 327.749 us; speedup vs baseline: 2.6872x; 1.2566x over previous
//
#include <hip/hip_runtime.h>
#include <stdint.h>

#define N_NODES 3072
#define D_IN    256
#define HIDDEN  384
#define HEADS   6
#define NH1     64
#define C1      1152   // 3*HIDDEN
#define C2      768    // 3*D_IN
#define MASK_ULL   48  // 3072/64 per row
#define MASK_BYTES 384 // 3072/8 per row
#define MASK_BSTRIDE ((size_t)N_NODES * MASK_BYTES)  // per-branch mask stride (bytes)
#define CHUNK   2048   // j-span per block (4 waves x 512)
#define MAXQ    2      // ceil(3072/CHUNK)
#define LOG2E   1.4426950408889634f

typedef __bf16 bf16;
typedef __bf16 bf16x8 __attribute__((ext_vector_type(8)));
typedef __bf16 bf16x4 __attribute__((ext_vector_type(4)));
typedef float  f32x4  __attribute__((ext_vector_type(4)));

__device__ __forceinline__ void atomAddF(float* p, float v) {
  __hip_atomic_fetch_add(p, v, __ATOMIC_RELAXED, __HIP_MEMORY_SCOPE_AGENT);
}
__device__ __forceinline__ float fexp2(float x) {   // D = 2^S0
  float r; asm("v_exp_f32 %0, %1" : "=v"(r) : "v"(x)); return r;
}

// ---------------------------------------------------------------- cast fp32->bf16
struct CastArgs {
  const float* src[11];
  bf16*        dst[11];
  int          cum4[12];
};

__global__ __launch_bounds__(256) void cast_all_kernel(CastArgs A) {
  int g = blockIdx.x * 256 + threadIdx.x;
  int j = 0;
#pragma unroll
  for (int k = 1; k < 11; ++k) j += (g >= A.cum4[k]);
  int e = (g - A.cum4[j]) * 4;
  float4 v = *(const float4*)(A.src[j] + e);
  bf16x4 o = { (bf16)v.x, (bf16)v.y, (bf16)v.z, (bf16)v.w };
  *(bf16x4*)(A.dst[j] + e) = o;
}

// ---------------------------------------------------------------- adj -> 3 per-branch bitmasks (range folded in)
__global__ __launch_bounds__(256) void pack_adj_kernel(const int* __restrict__ adj,
                                                       unsigned long long* __restrict__ maskU,
                                                       const int* __restrict__ dnum,
                                                       const int* __restrict__ snum) {
  int dn = dnum[0], sn = snum[0];
  int bb1 = N_NODES - sn - dn, bb2 = N_NODES - dn;
  int row = blockIdx.x;
  const int* ar = adj + (size_t)row * N_NODES;
  int lane = threadIdx.x & 63, wave = threadIdx.x >> 6;
#pragma unroll
  for (int it = 0; it < N_NODES / 256; ++it) {
    int j = it * 256 + wave * 64 + lane;
    bool a = ar[j] != 0;
    unsigned long long m0 = __ballot(a && (j < bb1));
    unsigned long long m1 = __ballot(a && (j >= bb1) && (j < bb2));
    unsigned long long m2 = __ballot(a && (j >= bb2));
    if (lane == 0) {
      size_t o = (size_t)row * MASK_ULL + it * 4 + wave;
      maskU[o] = m0;
      maskU[o + (size_t)N_NODES * MASK_ULL] = m1;
      maskU[o + 2 * (size_t)N_NODES * MASK_ULL] = m2;
    }
  }
}

// ---------------------------------------------------------------- pack g[j][f] -> gP[j/8][f][8]  (coalesced MFMA B-frags)
template<int C>
__global__ __launch_bounds__(256) void pack_kernel(const bf16* __restrict__ src,
                                                   bf16* __restrict__ dst) {
  __shared__ bf16 t[64][72];
  int j0 = blockIdx.x * 64, f0 = blockIdx.y * 64;
  int rr = threadIdx.x >> 4;
  int cc = (threadIdx.x & 15) * 4;
#pragma unroll
  for (int p = 0; p < 4; ++p) {
    int r = p * 16 + rr;
    *(bf16x4*)&t[r][cc] = *(const bf16x4*)&src[(size_t)(j0 + r) * C + f0 + cc];
  }
  __syncthreads();
  int f = threadIdx.x & 63, g = threadIdx.x >> 6;
#pragma unroll
  for (int q = 0; q < 2; ++q) {
    int p = g * 2 + q;
    bf16x8 v = { t[p*8+0][f], t[p*8+1][f], t[p*8+2][f], t[p*8+3][f],
                 t[p*8+4][f], t[p*8+5][f], t[p*8+6][f], t[p*8+7][f] };
    *(bf16x8*)&dst[ ((size_t)((j0 >> 3) + p) * C + f0 + f) * 8 ] = v;
  }
}

// ---------------------------------------------------------------- sl/sr projections (pre-scaled by log2(e))
template<int NHEADS, int NH>
__global__ __launch_bounds__(256) void head_proj_kernel(
    const bf16* __restrict__ g, int ldg,
    const float* __restrict__ a0, const float* __restrict__ a1, const float* __restrict__ a2,
    float* __restrict__ sl, float* __restrict__ sr) {
  int tid = blockIdx.x * 256 + threadIdx.x;
  int c = tid / N_NODES, i = tid - c * N_NODES;
  int b = c / NHEADS, h = c - b * NHEADS;
  const float* a = (b == 0) ? a0 : (b == 1) ? a1 : a2;
  const bf16* gr = g + (size_t)i * ldg + b * (NHEADS * NH) + h * NH;
  float accl = 0.f, accr = 0.f;
#pragma unroll 4
  for (int f = 0; f < NH; f += 4) {
    bf16x4 v = *(const bf16x4*)&gr[f];
#pragma unroll
    for (int k = 0; k < 4; ++k) {
      float gv = (float)v[k];
      accl += gv * a[f + k];
      accr += gv * a[NH + f + k];
    }
  }
  sl[c * N_NODES + i] = accl * LOG2E;
  sr[c * N_NODES + i] = accr * LOG2E;
}

// ---------------------------------------------------------------- column means (uniform-softmax fallback)
__global__ __launch_bounds__(256) void colmean_kernel(const bf16* __restrict__ g, int C,
                                                      float* __restrict__ out) {
  int c = blockIdx.x * 256 + threadIdx.x;
  if (c >= C) return;
  int r0 = blockIdx.y * 128;
  float s = 0.f;
  for (int r = r0; r < r0 + 128; ++r) s += (float)g[(size_t)r * C + c];
  atomAddF(&out[c], s * (1.0f / N_NODES));
}

// ---------------------------------------------------------------- GEMM 64x64 tile: C = A * B^T (+bias, leaky, +res)
template<bool BIAS, bool LEAKY, bool RES, bool F32OUT>
__global__ __launch_bounds__(256) void gemm64_kernel(
    const bf16* __restrict__ A, int lda, int aZoff,
    const bf16* __restrict__ B0, const bf16* __restrict__ B1, const bf16* __restrict__ B2,
    int ldb, void* __restrict__ Cout, int ldc, int cZoff, int K,
    const float* __restrict__ bias, const float* __restrict__ res) {
  __shared__ bf16 As[64 * 64];
  __shared__ bf16 Bs[64 * 64];
  int z = blockIdx.z;
  const bf16* Ab = A + (size_t)z * aZoff;
  const bf16* Bb = (z == 0) ? B0 : (z == 1) ? B1 : B2;
  int m0 = blockIdx.x * 64, n0 = blockIdx.y * 64;
  int tid = threadIdx.x;
  int lane = tid & 63, wave = tid >> 6;
  int wm = wave >> 1, wn = wave & 1;
  int l15 = lane & 15, lk = lane >> 4;
  f32x4 acc[2][2] = {};
  for (int kt = 0; kt < K; kt += 64) {
#pragma unroll
    for (int h = 0; h < 2; ++h) {
      int u = h * 256 + tid;
      int r = u >> 3, up = u & 7;
      int ul = up ^ (r & 7);
      *(bf16x8*)&As[r * 64 + up * 8] = *(const bf16x8*)&Ab[(size_t)(m0 + r) * lda + kt + ul * 8];
      *(bf16x8*)&Bs[r * 64 + up * 8] = *(const bf16x8*)&Bb[(size_t)(n0 + r) * ldb + kt + ul * 8];
    }
    __syncthreads();
#pragma unroll
    for (int s = 0; s < 2; ++s) {
      bf16x8 af[2], bfr[2];
      int u = s * 4 + lk;
#pragma unroll
      for (int mi = 0; mi < 2; ++mi) {
        int r = wm * 32 + mi * 16 + l15;
        af[mi] = *(const bf16x8*)&As[r * 64 + (u ^ (r & 7)) * 8];
      }
#pragma unroll
      for (int ni = 0; ni < 2; ++ni) {
        int r = wn * 32 + ni * 16 + l15;
        bfr[ni] = *(const bf16x8*)&Bs[r * 64 + (u ^ (r & 7)) * 8];
      }
#pragma unroll
      for (int mi = 0; mi < 2; ++mi)
#pragma unroll
        for (int ni = 0; ni < 2; ++ni)
          acc[mi][ni] = __builtin_amdgcn_mfma_f32_16x16x32_bf16(af[mi], bfr[ni], acc[mi][ni], 0, 0, 0);
    }
    __syncthreads();
  }
#pragma unroll
  for (int mi = 0; mi < 2; ++mi)
#pragma unroll
    for (int ni = 0; ni < 2; ++ni)
#pragma unroll
      for (int r = 0; r < 4; ++r) {
        int i = m0 + wm * 32 + mi * 16 + lk * 4 + r;
        int col = z * cZoff + n0 + wn * 32 + ni * 16 + l15;
        float v = acc[mi][ni][r];
        if (BIAS) v += bias[col];
        if (LEAKY) v = (v >= 0.f) ? v : 0.01f * v;
        if (RES) v += res[(size_t)i * ldc + col];
        if (F32OUT) ((float*)Cout)[(size_t)i * ldc + col] = v;
        else        ((bf16*)Cout)[(size_t)i * ldc + col] = (bf16)v;
      }
}

// ---------------------------------------------------------------- unified attention partial kernel
// block = (i_tile of 16 rows) x (combo) x (2048-j chunk); 4 waves split chunk 4x512.
// Writes one [16][64] f32 partial tile + 16 l-partials per block. No atomics.
template<bool L1>
__global__ __launch_bounds__(256) void att_kernel(
    const bf16* __restrict__ gP, const float* __restrict__ slA, const float* __restrict__ srA,
    const unsigned char* __restrict__ maskB,
    const int* __restrict__ dnum, const int* __restrict__ snum,
    float* __restrict__ accP, float* __restrict__ lP) {
  constexpr int C = L1 ? C1 : C2;
  int c = blockIdx.y;
  int b = L1 ? (c / 6) : (c >> 2);
  int colbase = L1 ? c * 64 : (b * 256 + (c & 3) * 64);
  int sidx = L1 ? c : b;
  int q = blockIdx.z;
  int dn = dnum[0], sn = snum[0];
  int bb1 = N_NODES - sn - dn, bb2 = N_NODES - dn;
  int jlo = (b == 0) ? 0 : (b == 1) ? bb1 : bb2;
  int jhi = (b == 0) ? bb1 : (b == 1) ? bb2 : N_NODES;
  int lo32 = jlo & ~31, hi32 = (jhi + 31) & ~31;
  int qlo = q * CHUNK, qhi = qlo + CHUNK;
  if (lo32 >= qhi || hi32 <= qlo) return;   // fin never reads this slot

  int wave = threadIdx.x >> 6, lane = threadIdx.x & 63;
  int l15 = lane & 15, lk = lane >> 4;
  int i0 = blockIdx.x * 16;
  int wlo = max(lo32, qlo + wave * (CHUNK / 4));
  int whi = min(hi32, qlo + (wave + 1) * (CHUNK / 4));
  int ip = i0 + l15;
  float sl = slA[sidx * N_NODES + ip];
  const float* srp = srA + sidx * N_NODES;
  const unsigned char* mrow = maskB + (size_t)b * MASK_BSTRIDE + (size_t)ip * MASK_BYTES;
  f32x4 acc[4] = {};
  float lsum = 0.f;
  for (int jt = wlo; jt < whi; jt += 32) {
    int jb = jt + lk * 8;
    unsigned int mb = mrow[jb >> 3];
    float4 s0 = *(const float4*)&srp[jb];
    float4 s1 = *(const float4*)&srp[jb + 4];
    float sv[8] = { s0.x, s0.y, s0.z, s0.w, s1.x, s1.y, s1.z, s1.w };
    bf16x8 a8;
#pragma unroll
    for (int e = 0; e < 8; ++e) {
      float x = sl + sv[e];
      x = fmaxf(x, 0.f) + 0.2f * fminf(x, 0.f);   // leaky (slope commutes with log2e prescale)
      float p = fexp2(x);                          // e^leaky(sl+sr), prescaled
      p = ((mb >> e) & 1u) ? p : 0.f;
      a8[e] = (bf16)p;
      lsum += p;
    }
    size_t pbase = (size_t)(jb >> 3) * C * 8;
#pragma unroll
    for (int nf = 0; nf < 4; ++nf) {
      bf16x8 b8 = *(const bf16x8*)&gP[pbase + (size_t)(colbase + nf * 16 + l15) * 8];
      acc[nf] = __builtin_amdgcn_mfma_f32_16x16x32_bf16(a8, b8, acc[nf], 0, 0, 0);
    }
  }
  lsum += __shfl_xor(lsum, 16, 64);
  lsum += __shfl_xor(lsum, 32, 64);

  __shared__ float red[4][16][64];
  __shared__ float redl[4][16];
#pragma unroll
  for (int nf = 0; nf < 4; ++nf)
#pragma unroll
    for (int r = 0; r < 4; ++r)
      red[wave][lk * 4 + r][nf * 16 + l15] = acc[nf][r];
  if (lane < 16) redl[wave][lane] = lsum;
  __syncthreads();
  int t = threadIdx.x;
  const float* rp = &red[0][0][0];
  f32x4 v = *(const f32x4*)(rp + t * 4);
  v += *(const f32x4*)(rp + 1024 + t * 4);
  v += *(const f32x4*)(rp + 2048 + t * 4);
  v += *(const f32x4*)(rp + 3072 + t * 4);
  int row = t >> 4, colg = (t & 15) * 4;
  int slot = c * MAXQ + q;
  *(f32x4*)&accP[((size_t)slot * N_NODES + i0 + row) * 64 + colg] = v;
  if (t < 16)
    lP[(size_t)slot * N_NODES + i0 + t] = redl[0][t] + redl[1][t] + redl[2][t] + redl[3][t];
}

// ---------------------------------------------------------------- finalize layer 1: sum slices, /l (or gmean), ELU
__global__ __launch_bounds__(256) void fin1_kernel(
    const float* __restrict__ accP, const float* __restrict__ lP,
    const float* __restrict__ gm, const int* __restrict__ dnum, const int* __restrict__ snum,
    bf16* __restrict__ out1) {
  int t = blockIdx.x * 256 + threadIdx.x;
  int i = t / (C1 / 8), f0 = (t - i * (C1 / 8)) * 8;
  int c = f0 >> 6;
  int b = c / 6;
  int dn = dnum[0], sn = snum[0];
  int bb1 = N_NODES - sn - dn, bb2 = N_NODES - dn;
  int jlo = (b == 0) ? 0 : (b == 1) ? bb1 : bb2;
  int jhi = (b == 0) ? bb1 : (b == 1) ? bb2 : N_NODES;
  float l = 0.f;
  float a[8] = {0.f,0.f,0.f,0.f,0.f,0.f,0.f,0.f};
  if (jhi > jlo) {
    int q0 = jlo >> 11, q1 = (jhi - 1) >> 11;
    for (int q = q0; q <= q1; ++q) {
      int slot = c * MAXQ + q;
      l += lP[(size_t)slot * N_NODES + i];
      const float* ap = &accP[((size_t)slot * N_NODES + i) * 64 + (f0 & 63)];
      f32x4 v0 = *(const f32x4*)ap, v1 = *(const f32x4*)(ap + 4);
#pragma unroll
      for (int e = 0; e < 4; ++e) { a[e] += v0[e]; a[e + 4] += v1[e]; }
    }
  }
  float inv = (l > 0.f) ? 1.f / l : 0.f;
  bf16x8 o;
#pragma unroll
  for (int e = 0; e < 8; ++e) {
    float v = (l > 0.f) ? a[e] * inv : gm[f0 + e];
    v = (v > 0.f) ? v : (__expf(v) - 1.f);   // ELU
    o[e] = (bf16)v;
  }
  *(bf16x8*)&out1[(size_t)i * C1 + f0] = o;
}

// ---------------------------------------------------------------- finalize layer 2: sum slices, /l (or gmean), +residual -> fused
__global__ __launch_bounds__(256) void fin2_kernel(
    const float* __restrict__ accP, const float* __restrict__ lP,
    const float* __restrict__ gm, const float* __restrict__ feat,
    const int* __restrict__ dnum, const int* __restrict__ snum,
    bf16* __restrict__ fused) {
  int t = blockIdx.x * 256 + threadIdx.x;
  int i = t / (C2 / 8), f0 = (t - i * (C2 / 8)) * 8;
  int b = f0 >> 8;
  int fi = f0 & 255;
  int fc = (f0 >> 6) & 3;
  int c = b * 4 + fc;
  int dn = dnum[0], sn = snum[0];
  int bb1 = N_NODES - sn - dn, bb2 = N_NODES - dn;
  int jlo = (b == 0) ? 0 : (b == 1) ? bb1 : bb2;
  int jhi = (b == 0) ? bb1 : (b == 1) ? bb2 : N_NODES;
  float l = 0.f;
  float a[8] = {0.f,0.f,0.f,0.f,0.f,0.f,0.f,0.f};
  if (jhi > jlo) {
    int q0 = jlo >> 11, q1 = (jhi - 1) >> 11;
    for (int q = q0; q <= q1; ++q) {
      int slot = c * MAXQ + q;
      l += lP[(size_t)slot * N_NODES + i];
      const float* ap = &accP[((size_t)slot * N_NODES + i) * 64 + (f0 & 63)];
      f32x4 v0 = *(const f32x4*)ap, v1 = *(const f32x4*)(ap + 4);
#pragma unroll
      for (int e = 0; e < 4; ++e) { a[e] += v0[e]; a[e + 4] += v1[e]; }
    }
  }
  float inv = (l > 0.f) ? 1.f / l : 0.f;
  bf16x8 o;
#pragma unroll
  for (int e = 0; e < 8; ++e) {
    float v = (l > 0.f) ? a[e] * inv : gm[f0 + e];
    v += feat[(size_t)i * D_IN + fi + e];
    o[e] = (bf16)v;
  }
  *(bf16x8*)&fused[(size_t)i * C2 + (2 - b) * D_IN + fi] = o;
}

// ---------------------------------------------------------------- launch
extern "C" void kernel_launch(void* const* d_in, const int* in_sizes, int n_in,
                              void* d_out, int out_size, void* d_ws, size_t ws_size,
                              hipStream_t stream) {
  (void)in_sizes; (void)n_in; (void)out_size; (void)ws_size;
  const float* feature = (const float*)d_in[0];
  const int*   adj     = (const int*)d_in[1];
  const int*   dnum    = (const int*)d_in[2];
  const int*   snum    = (const int*)d_in[3];
  const float* W1s = (const float*)d_in[4];  const float* a1s = (const float*)d_in[5];
  const float* W2s = (const float*)d_in[6];  const float* a2s = (const float*)d_in[7];
  const float* W1e = (const float*)d_in[8];  const float* a1e = (const float*)d_in[9];
  const float* W2e = (const float*)d_in[10]; const float* a2e = (const float*)d_in[11];
  const float* W1d = (const float*)d_in[12]; const float* a1d = (const float*)d_in[13];
  const float* W2d = (const float*)d_in[14]; const float* a2d = (const float*)d_in[15];
  const float* fW  = (const float*)d_in[16]; const float* fB  = (const float*)d_in[17];
  const float* w0  = (const float*)d_in[18]; const float* b0  = (const float*)d_in[19];
  const float* w1  = (const float*)d_in[20]; const float* b1  = (const float*)d_in[21];
  const float* w2  = (const float*)d_in[22]; const float* b2  = (const float*)d_in[23];

  char* ws = (char*)d_ws;
  size_t off = 0;
  auto alloc = [&](size_t bytes) { void* p = ws + off; off += (bytes + 255) & ~(size_t)255; return p; };

  unsigned long long* maskU = (unsigned long long*)alloc(3 * (size_t)N_NODES * MASK_ULL * 8);
  bf16* fbf   = (bf16*)alloc((size_t)N_NODES * D_IN * 2);
  bf16* w1b0  = (bf16*)alloc(HIDDEN * D_IN * 2);
  bf16* w1b1  = (bf16*)alloc(HIDDEN * D_IN * 2);
  bf16* w1b2  = (bf16*)alloc(HIDDEN * D_IN * 2);
  bf16* w2b0  = (bf16*)alloc(D_IN * HIDDEN * 2);
  bf16* w2b1  = (bf16*)alloc(D_IN * HIDDEN * 2);
  bf16* w2b2  = (bf16*)alloc(D_IN * HIDDEN * 2);
  bf16* wfusb = (bf16*)alloc(D_IN * C2 * 2);
  bf16* wf0b  = (bf16*)alloc(HIDDEN * D_IN * 2);
  bf16* wf1b  = (bf16*)alloc(HIDDEN * HIDDEN * 2);
  bf16* wf2b  = (bf16*)alloc(D_IN * HIDDEN * 2);
  bf16* g1    = (bf16*)alloc((size_t)N_NODES * C1 * 2);
  bf16* gP1   = (bf16*)alloc((size_t)N_NODES * C1 * 2);
  bf16* out1  = (bf16*)alloc((size_t)N_NODES * C1 * 2);
  bf16* g2    = (bf16*)alloc((size_t)N_NODES * C2 * 2);
  bf16* gP2   = (bf16*)alloc((size_t)N_NODES * C2 * 2);
  bf16* fusedB= (bf16*)alloc((size_t)N_NODES * C2 * 2);
  bf16* h0    = (bf16*)alloc((size_t)N_NODES * D_IN * 2);
  bf16* h1    = (bf16*)alloc((size_t)N_NODES * HIDDEN * 2);
  bf16* h2    = (bf16*)alloc((size_t)N_NODES * HIDDEN * 2);
  float* sl1  = (float*)alloc(18 * N_NODES * 4);
  float* sr1  = (float*)alloc(18 * N_NODES * 4);
  float* sl2  = (float*)alloc(3 * N_NODES * 4);
  float* sr2  = (float*)alloc(3 * N_NODES * 4);
  // partial buffers: att1 and att2 phases don't overlap -> union
  float* accU = (float*)alloc((size_t)18 * MAXQ * N_NODES * 64 * 4);  // 28.3 MB (att1); att2 uses 24 slots
  float* lU   = (float*)alloc((size_t)18 * MAXQ * N_NODES * 4);
  // zero-initialized region: colmeans only
  size_t zoff = off;
  float* gm1  = (float*)alloc(C1 * 4);
  float* gm2  = (float*)alloc(C2 * 4);
  size_t zbytes = off - zoff;
  const unsigned char* maskBytes = (const unsigned char*)maskU;

  hipMemsetAsync(ws + zoff, 0, zbytes, stream);

  // 1) casts
  CastArgs ca;
  {
    const float* srcs[11] = { feature, W1s, W1e, W1d, W2s, W2e, W2d, fW, w0, w1, w2 };
    bf16* dsts[11] = { fbf, w1b0, w1b1, w1b2, w2b0, w2b1, w2b2, wfusb, wf0b, wf1b, wf2b };
    int counts[11] = { N_NODES*D_IN, HIDDEN*D_IN, HIDDEN*D_IN, HIDDEN*D_IN,
                       D_IN*HIDDEN, D_IN*HIDDEN, D_IN*HIDDEN, D_IN*C2,
                       HIDDEN*D_IN, HIDDEN*HIDDEN, D_IN*HIDDEN };
    int cum = 0;
    for (int k = 0; k < 11; ++k) { ca.src[k] = srcs[k]; ca.dst[k] = dsts[k]; ca.cum4[k] = cum; cum += counts[k] / 4; }
    ca.cum4[11] = cum;
    cast_all_kernel<<<cum / 256, 256, 0, stream>>>(ca);
  }
  // 2) pack adjacency bits (3 per-branch masks, range folded in)
  pack_adj_kernel<<<N_NODES, 256, 0, stream>>>(adj, maskU, dnum, snum);
  // 3) g1 = f @ W1^T (3 branches via z)
  gemm64_kernel<false,false,false,false><<<dim3(48,6,3), 256, 0, stream>>>(
      fbf, D_IN, 0, w1b0, w1b1, w1b2, D_IN, g1, C1, HIDDEN, D_IN, nullptr, nullptr);
  // 4) pack g1 -> gP1
  pack_kernel<C1><<<dim3(48,18), 256, 0, stream>>>(g1, gP1);
  // 5) sl/sr layer1 (prescaled by log2e)
  head_proj_kernel<HEADS, NH1><<<18 * N_NODES / 256, 256, 0, stream>>>(g1, C1, a1s, a1e, a1d, sl1, sr1);
  // 6) colmean g1
  colmean_kernel<<<dim3((C1 + 255) / 256, 24), 256, 0, stream>>>(g1, C1, gm1);
  // 7) attention 1 partials
  att_kernel<true><<<dim3(192, 18, MAXQ), 256, 0, stream>>>(gP1, sl1, sr1, maskBytes, dnum, snum, accU, lU);
  // 7b) finalize 1 (+ELU)
  fin1_kernel<<<N_NODES * (C1 / 8) / 256, 256, 0, stream>>>(accU, lU, gm1, dnum, snum, out1);
  // 8) g2 = out1 @ W2^T per branch
  gemm64_kernel<false,false,false,false><<<dim3(48,4,3), 256, 0, stream>>>(
      out1, C1, HIDDEN, w2b0, w2b1, w2b2, HIDDEN, g2, C2, D_IN, HIDDEN, nullptr, nullptr);
  // 9) pack g2 -> gP2
  pack_kernel<C2><<<dim3(48,12), 256, 0, stream>>>(g2, gP2);
  // 10) sl/sr layer2
  head_proj_kernel<1, D_IN><<<3 * N_NODES / 256, 256, 0, stream>>>(g2, C2, a2s, a2e, a2d, sl2, sr2);
  // 11) colmean g2
  colmean_kernel<<<dim3((C2 + 255) / 256, 24), 256, 0, stream>>>(g2, C2, gm2);
  // 12) attention 2 partials (combos = branch x 4 f-chunks)
  att_kernel<false><<<dim3(192, 12, MAXQ), 256, 0, stream>>>(gP2, sl2, sr2, maskBytes, dnum, snum, accU, lU);
  // 12b) finalize 2 (+residual, writes fused [doc,sect,sent])
  fin2_kernel<<<N_NODES * (C2 / 8) / 256, 256, 0, stream>>>(accU, lU, gm2, feature, dnum, snum, fusedB);
  // 13) fusion: h0 = leaky(fused @ fW^T + fB)
  gemm64_kernel<true,true,false,false><<<dim3(48,4,1), 256, 0, stream>>>(
      fusedB, C2, 0, wfusb, wfusb, wfusb, C2, h0, D_IN, 0, C2, fB, nullptr);
  // 14) ffn0: h1 = leaky(h0 @ w0^T + b0)
  gemm64_kernel<true,true,false,false><<<dim3(48,6,1), 256, 0, stream>>>(
      h0, D_IN, 0, wf0b, wf0b, wf0b, D_IN, h1, HIDDEN, 0, D_IN, b0, nullptr);
  // 15) ffn1: h2 = leaky(h1 @ w1^T + b1)
  gemm64_kernel<true,true,false,false><<<dim3(48,6,1), 256, 0, stream>>>(
      h1, HIDDEN, 0, wf1b, wf1b, wf1b, HIDDEN, h2, HIDDEN, 0, HIDDEN, b1, nullptr);
  // 16) ffn2: out = leaky(h2 @ w2^T + b2) + f   (fp32 out)
  gemm64_kernel<true,true,true,true><<<dim3(48,4,1), 256, 0, stream>>>(
      h2, HIDDEN, 0, wf2b, wf2b, wf2b, HIDDEN, d_out, D_IN, 0, HIDDEN, b2, feature);
}

// Round 4
// 310.858 us; speedup vs baseline: 2.8333x; 1.0543x over previous
//
#include <hip/hip_runtime.h>
#include <stdint.h>

#define N_NODES 3072
#define D_IN    256
#define HIDDEN  384
#define HEADS   6
#define NH1     64
#define C1      1152   // 3*HIDDEN
#define C2      768    // 3*D_IN
#define MASK_ULL   48  // 3072/64 per row
#define MASK_BYTES 384 // 3072/8 per row
#define MASK_BSTRIDE ((size_t)N_NODES * MASK_BYTES)  // per-branch mask stride (bytes)
#define CHUNK   1536   // j-span per block (all 4 waves traverse it; waves own rows)
#define MAXQ    2      // ceil(3072/CHUNK)
#define LOG2E   1.4426950408889634f

typedef __bf16 bf16;
typedef __bf16 bf16x8 __attribute__((ext_vector_type(8)));
typedef __bf16 bf16x4 __attribute__((ext_vector_type(4)));
typedef float  f32x4  __attribute__((ext_vector_type(4)));

__device__ __forceinline__ void atomAddF(float* p, float v) {
  __hip_atomic_fetch_add(p, v, __ATOMIC_RELAXED, __HIP_MEMORY_SCOPE_AGENT);
}
__device__ __forceinline__ float fexp2(float x) {   // D = 2^S0
  float r; asm("v_exp_f32 %0, %1" : "=v"(r) : "v"(x)); return r;
}

// ---------------------------------------------------------------- cast fp32->bf16
struct CastArgs {
  const float* src[11];
  bf16*        dst[11];
  int          cum4[12];
};

__global__ __launch_bounds__(256) void cast_all_kernel(CastArgs A) {
  int g = blockIdx.x * 256 + threadIdx.x;
  int j = 0;
#pragma unroll
  for (int k = 1; k < 11; ++k) j += (g >= A.cum4[k]);
  int e = (g - A.cum4[j]) * 4;
  float4 v = *(const float4*)(A.src[j] + e);
  bf16x4 o = { (bf16)v.x, (bf16)v.y, (bf16)v.z, (bf16)v.w };
  *(bf16x4*)(A.dst[j] + e) = o;
}

// ---------------------------------------------------------------- adj -> 3 per-branch bitmasks (range folded in)
__global__ __launch_bounds__(256) void pack_adj_kernel(const int* __restrict__ adj,
                                                       unsigned long long* __restrict__ maskU,
                                                       const int* __restrict__ dnum,
                                                       const int* __restrict__ snum) {
  int dn = dnum[0], sn = snum[0];
  int bb1 = N_NODES - sn - dn, bb2 = N_NODES - dn;
  int row = blockIdx.x;
  const int* ar = adj + (size_t)row * N_NODES;
  int lane = threadIdx.x & 63, wave = threadIdx.x >> 6;
#pragma unroll
  for (int it = 0; it < N_NODES / 256; ++it) {
    int j = it * 256 + wave * 64 + lane;
    bool a = ar[j] != 0;
    unsigned long long m0 = __ballot(a && (j < bb1));
    unsigned long long m1 = __ballot(a && (j >= bb1) && (j < bb2));
    unsigned long long m2 = __ballot(a && (j >= bb2));
    if (lane == 0) {
      size_t o = (size_t)row * MASK_ULL + it * 4 + wave;
      maskU[o] = m0;
      maskU[o + (size_t)N_NODES * MASK_ULL] = m1;
      maskU[o + 2 * (size_t)N_NODES * MASK_ULL] = m2;
    }
  }
}

// ---------------------------------------------------------------- pack g[j][f] -> gP[j/8][f][8]  (coalesced MFMA B-frags)
template<int C>
__global__ __launch_bounds__(256) void pack_kernel(const bf16* __restrict__ src,
                                                   bf16* __restrict__ dst) {
  __shared__ bf16 t[64][72];
  int j0 = blockIdx.x * 64, f0 = blockIdx.y * 64;
  int rr = threadIdx.x >> 4;
  int cc = (threadIdx.x & 15) * 4;
#pragma unroll
  for (int p = 0; p < 4; ++p) {
    int r = p * 16 + rr;
    *(bf16x4*)&t[r][cc] = *(const bf16x4*)&src[(size_t)(j0 + r) * C + f0 + cc];
  }
  __syncthreads();
  int f = threadIdx.x & 63, g = threadIdx.x >> 6;
#pragma unroll
  for (int q = 0; q < 2; ++q) {
    int p = g * 2 + q;
    bf16x8 v = { t[p*8+0][f], t[p*8+1][f], t[p*8+2][f], t[p*8+3][f],
                 t[p*8+4][f], t[p*8+5][f], t[p*8+6][f], t[p*8+7][f] };
    *(bf16x8*)&dst[ ((size_t)((j0 >> 3) + p) * C + f0 + f) * 8 ] = v;
  }
}

// ---------------------------------------------------------------- sl/sr projections (pre-scaled by log2(e))
template<int NHEADS, int NH>
__global__ __launch_bounds__(256) void head_proj_kernel(
    const bf16* __restrict__ g, int ldg,
    const float* __restrict__ a0, const float* __restrict__ a1, const float* __restrict__ a2,
    float* __restrict__ sl, float* __restrict__ sr) {
  int tid = blockIdx.x * 256 + threadIdx.x;
  int c = tid / N_NODES, i = tid - c * N_NODES;
  int b = c / NHEADS, h = c - b * NHEADS;
  const float* a = (b == 0) ? a0 : (b == 1) ? a1 : a2;
  const bf16* gr = g + (size_t)i * ldg + b * (NHEADS * NH) + h * NH;
  float accl = 0.f, accr = 0.f;
#pragma unroll 4
  for (int f = 0; f < NH; f += 4) {
    bf16x4 v = *(const bf16x4*)&gr[f];
#pragma unroll
    for (int k = 0; k < 4; ++k) {
      float gv = (float)v[k];
      accl += gv * a[f + k];
      accr += gv * a[NH + f + k];
    }
  }
  sl[c * N_NODES + i] = accl * LOG2E;
  sr[c * N_NODES + i] = accr * LOG2E;
}

// ---------------------------------------------------------------- column means (uniform-softmax fallback)
__global__ __launch_bounds__(256) void colmean_kernel(const bf16* __restrict__ g, int C,
                                                      float* __restrict__ out) {
  int c = blockIdx.x * 256 + threadIdx.x;
  if (c >= C) return;
  int r0 = blockIdx.y * 128;
  float s = 0.f;
  for (int r = r0; r < r0 + 128; ++r) s += (float)g[(size_t)r * C + c];
  atomAddF(&out[c], s * (1.0f / N_NODES));
}

// ---------------------------------------------------------------- GEMM 64x64 tile: C = A * B^T (+bias, leaky, +res)
template<bool BIAS, bool LEAKY, bool RES, bool F32OUT>
__global__ __launch_bounds__(256) void gemm64_kernel(
    const bf16* __restrict__ A, int lda, int aZoff,
    const bf16* __restrict__ B0, const bf16* __restrict__ B1, const bf16* __restrict__ B2,
    int ldb, void* __restrict__ Cout, int ldc, int cZoff, int K,
    const float* __restrict__ bias, const float* __restrict__ res) {
  __shared__ bf16 As[64 * 64];
  __shared__ bf16 Bs[64 * 64];
  int z = blockIdx.z;
  const bf16* Ab = A + (size_t)z * aZoff;
  const bf16* Bb = (z == 0) ? B0 : (z == 1) ? B1 : B2;
  int m0 = blockIdx.x * 64, n0 = blockIdx.y * 64;
  int tid = threadIdx.x;
  int lane = tid & 63, wave = tid >> 6;
  int wm = wave >> 1, wn = wave & 1;
  int l15 = lane & 15, lk = lane >> 4;
  f32x4 acc[2][2] = {};
  for (int kt = 0; kt < K; kt += 64) {
#pragma unroll
    for (int h = 0; h < 2; ++h) {
      int u = h * 256 + tid;
      int r = u >> 3, up = u & 7;
      int ul = up ^ (r & 7);
      *(bf16x8*)&As[r * 64 + up * 8] = *(const bf16x8*)&Ab[(size_t)(m0 + r) * lda + kt + ul * 8];
      *(bf16x8*)&Bs[r * 64 + up * 8] = *(const bf16x8*)&Bb[(size_t)(n0 + r) * ldb + kt + ul * 8];
    }
    __syncthreads();
#pragma unroll
    for (int s = 0; s < 2; ++s) {
      bf16x8 af[2], bfr[2];
      int u = s * 4 + lk;
#pragma unroll
      for (int mi = 0; mi < 2; ++mi) {
        int r = wm * 32 + mi * 16 + l15;
        af[mi] = *(const bf16x8*)&As[r * 64 + (u ^ (r & 7)) * 8];
      }
#pragma unroll
      for (int ni = 0; ni < 2; ++ni) {
        int r = wn * 32 + ni * 16 + l15;
        bfr[ni] = *(const bf16x8*)&Bs[r * 64 + (u ^ (r & 7)) * 8];
      }
#pragma unroll
      for (int mi = 0; mi < 2; ++mi)
#pragma unroll
        for (int ni = 0; ni < 2; ++ni)
          acc[mi][ni] = __builtin_amdgcn_mfma_f32_16x16x32_bf16(af[mi], bfr[ni], acc[mi][ni], 0, 0, 0);
    }
    __syncthreads();
  }
#pragma unroll
  for (int mi = 0; mi < 2; ++mi)
#pragma unroll
    for (int ni = 0; ni < 2; ++ni)
#pragma unroll
      for (int r = 0; r < 4; ++r) {
        int i = m0 + wm * 32 + mi * 16 + lk * 4 + r;
        int col = z * cZoff + n0 + wn * 32 + ni * 16 + l15;
        float v = acc[mi][ni][r];
        if (BIAS) v += bias[col];
        if (LEAKY) v = (v >= 0.f) ? v : 0.01f * v;
        if (RES) v += res[(size_t)i * ldc + col];
        if (F32OUT) ((float*)Cout)[(size_t)i * ldc + col] = v;
        else        ((bf16*)Cout)[(size_t)i * ldc + col] = (bf16)v;
      }
}

// ---------------------------------------------------------------- unified attention partial kernel
// block = 64 rows x (combo) x (1536-j chunk). Wave w owns rows [i0+16w, i0+16w+16),
// traverses the FULL chunk -> all 4 waves read the same gP stream (L1 reuse).
// No LDS, no barriers, no atomics. Denominator = 5th MFMA with B = ones.
template<bool L1>
__global__ __launch_bounds__(256) void att_kernel(
    const bf16* __restrict__ gP, const float* __restrict__ slA, const float* __restrict__ srA,
    const unsigned char* __restrict__ maskB,
    const int* __restrict__ dnum, const int* __restrict__ snum,
    float* __restrict__ accP, float* __restrict__ lP) {
  constexpr int C = L1 ? C1 : C2;
  int c = blockIdx.y;
  int b = L1 ? (c / 6) : (c >> 2);
  int colbase = L1 ? c * 64 : (b * 256 + (c & 3) * 64);
  int sidx = L1 ? c : b;
  int q = blockIdx.z;
  int dn = dnum[0], sn = snum[0];
  int bb1 = N_NODES - sn - dn, bb2 = N_NODES - dn;
  int jlo = (b == 0) ? 0 : (b == 1) ? bb1 : bb2;
  int jhi = (b == 0) ? bb1 : (b == 1) ? bb2 : N_NODES;
  int lo32 = jlo & ~31, hi32 = (jhi + 31) & ~31;
  int qlo = q * CHUNK, qhi = qlo + CHUNK;
  int wlo = max(lo32, qlo), whi = min(hi32, qhi);
  if (wlo >= whi) return;   // fin never reads this slot

  int wave = threadIdx.x >> 6, lane = threadIdx.x & 63;
  int l15 = lane & 15, lk = lane >> 4;
  int row0 = blockIdx.x * 64 + wave * 16;
  int ip = row0 + l15;
  float sl = slA[sidx * N_NODES + ip];
  const float* srp = srA + sidx * N_NODES;
  const unsigned char* mrow = maskB + (size_t)b * MASK_BSTRIDE + (size_t)ip * MASK_BYTES;
  bf16x8 ones;
#pragma unroll
  for (int e = 0; e < 8; ++e) ones[e] = (bf16)1.0f;
  f32x4 acc[4] = {};
  f32x4 accl = {};
  for (int jt = wlo; jt < whi; jt += 32) {
    int jb = jt + lk * 8;
    unsigned int mb = mrow[jb >> 3];
    float4 s0 = *(const float4*)&srp[jb];
    float4 s1 = *(const float4*)&srp[jb + 4];
    float sv[8] = { s0.x, s0.y, s0.z, s0.w, s1.x, s1.y, s1.z, s1.w };
    bf16x8 a8;
#pragma unroll
    for (int e = 0; e < 8; ++e) {
      float x = sl + sv[e];
      x = fmaf(fminf(x, 0.f), -0.8f, x);          // leaky slope 0.2 (log2e prescaled)
      float p = fexp2(x);
      p = ((mb >> e) & 1u) ? p : 0.f;
      a8[e] = (bf16)p;
    }
    size_t pbase = (size_t)(jb >> 3) * C * 8;
#pragma unroll
    for (int nf = 0; nf < 4; ++nf) {
      bf16x8 b8 = *(const bf16x8*)&gP[pbase + (size_t)(colbase + nf * 16 + l15) * 8];
      acc[nf] = __builtin_amdgcn_mfma_f32_16x16x32_bf16(a8, b8, acc[nf], 0, 0, 0);
    }
    accl = __builtin_amdgcn_mfma_f32_16x16x32_bf16(a8, ones, accl, 0, 0, 0);
  }
  int slot = c * MAXQ + q;
  float* ap = accP + ((size_t)slot * N_NODES + row0) * 64;
#pragma unroll
  for (int nf = 0; nf < 4; ++nf)
#pragma unroll
    for (int r = 0; r < 4; ++r)
      ap[(lk * 4 + r) * 64 + nf * 16 + l15] = acc[nf][r];
  if (l15 == 0) {
#pragma unroll
    for (int r = 0; r < 4; ++r)
      lP[(size_t)slot * N_NODES + row0 + lk * 4 + r] = accl[r];
  }
}

// ---------------------------------------------------------------- finalize layer 1: sum slices, /l (or gmean), ELU
__global__ __launch_bounds__(256) void fin1_kernel(
    const float* __restrict__ accP, const float* __restrict__ lP,
    const float* __restrict__ gm, const int* __restrict__ dnum, const int* __restrict__ snum,
    bf16* __restrict__ out1) {
  int t = blockIdx.x * 256 + threadIdx.x;
  int i = t / (C1 / 8), f0 = (t - i * (C1 / 8)) * 8;
  int c = f0 >> 6;
  int b = c / 6;
  int dn = dnum[0], sn = snum[0];
  int bb1 = N_NODES - sn - dn, bb2 = N_NODES - dn;
  int jlo = (b == 0) ? 0 : (b == 1) ? bb1 : bb2;
  int jhi = (b == 0) ? bb1 : (b == 1) ? bb2 : N_NODES;
  float l = 0.f;
  float a[8] = {0.f,0.f,0.f,0.f,0.f,0.f,0.f,0.f};
  if (jhi > jlo) {
    int q0 = jlo / CHUNK, q1 = (jhi - 1) / CHUNK;
    for (int q = q0; q <= q1; ++q) {
      int slot = c * MAXQ + q;
      l += lP[(size_t)slot * N_NODES + i];
      const float* ap = &accP[((size_t)slot * N_NODES + i) * 64 + (f0 & 63)];
      f32x4 v0 = *(const f32x4*)ap, v1 = *(const f32x4*)(ap + 4);
#pragma unroll
      for (int e = 0; e < 4; ++e) { a[e] += v0[e]; a[e + 4] += v1[e]; }
    }
  }
  float inv = (l > 0.f) ? 1.f / l : 0.f;
  bf16x8 o;
#pragma unroll
  for (int e = 0; e < 8; ++e) {
    float v = (l > 0.f) ? a[e] * inv : gm[f0 + e];
    v = (v > 0.f) ? v : (__expf(v) - 1.f);   // ELU
    o[e] = (bf16)v;
  }
  *(bf16x8*)&out1[(size_t)i * C1 + f0] = o;
}

// ---------------------------------------------------------------- finalize layer 2: sum slices, /l (or gmean), +residual -> fused
__global__ __launch_bounds__(256) void fin2_kernel(
    const float* __restrict__ accP, const float* __restrict__ lP,
    const float* __restrict__ gm, const float* __restrict__ feat,
    const int* __restrict__ dnum, const int* __restrict__ snum,
    bf16* __restrict__ fused) {
  int t = blockIdx.x * 256 + threadIdx.x;
  int i = t / (C2 / 8), f0 = (t - i * (C2 / 8)) * 8;
  int b = f0 >> 8;
  int fi = f0 & 255;
  int fc = (f0 >> 6) & 3;
  int c = b * 4 + fc;
  int dn = dnum[0], sn = snum[0];
  int bb1 = N_NODES - sn - dn, bb2 = N_NODES - dn;
  int jlo = (b == 0) ? 0 : (b == 1) ? bb1 : bb2;
  int jhi = (b == 0) ? bb1 : (b == 1) ? bb2 : N_NODES;
  float l = 0.f;
  float a[8] = {0.f,0.f,0.f,0.f,0.f,0.f,0.f,0.f};
  if (jhi > jlo) {
    int q0 = jlo / CHUNK, q1 = (jhi - 1) / CHUNK;
    for (int q = q0; q <= q1; ++q) {
      int slot = c * MAXQ + q;
      l += lP[(size_t)slot * N_NODES + i];
      const float* ap = &accP[((size_t)slot * N_NODES + i) * 64 + (f0 & 63)];
      f32x4 v0 = *(const f32x4*)ap, v1 = *(const f32x4*)(ap + 4);
#pragma unroll
      for (int e = 0; e < 4; ++e) { a[e] += v0[e]; a[e + 4] += v1[e]; }
    }
  }
  float inv = (l > 0.f) ? 1.f / l : 0.f;
  bf16x8 o;
#pragma unroll
  for (int e = 0; e < 8; ++e) {
    float v = (l > 0.f) ? a[e] * inv : gm[f0 + e];
    v += feat[(size_t)i * D_IN + fi + e];
    o[e] = (bf16)v;
  }
  *(bf16x8*)&fused[(size_t)i * C2 + (2 - b) * D_IN + fi] = o;
}

// ---------------------------------------------------------------- launch
extern "C" void kernel_launch(void* const* d_in, const int* in_sizes, int n_in,
                              void* d_out, int out_size, void* d_ws, size_t ws_size,
                              hipStream_t stream) {
  (void)in_sizes; (void)n_in; (void)out_size; (void)ws_size;
  const float* feature = (const float*)d_in[0];
  const int*   adj     = (const int*)d_in[1];
  const int*   dnum    = (const int*)d_in[2];
  const int*   snum    = (const int*)d_in[3];
  const float* W1s = (const float*)d_in[4];  const float* a1s = (const float*)d_in[5];
  const float* W2s = (const float*)d_in[6];  const float* a2s = (const float*)d_in[7];
  const float* W1e = (const float*)d_in[8];  const float* a1e = (const float*)d_in[9];
  const float* W2e = (const float*)d_in[10]; const float* a2e = (const float*)d_in[11];
  const float* W1d = (const float*)d_in[12]; const float* a1d = (const float*)d_in[13];
  const float* W2d = (const float*)d_in[14]; const float* a2d = (const float*)d_in[15];
  const float* fW  = (const float*)d_in[16]; const float* fB  = (const float*)d_in[17];
  const float* w0  = (const float*)d_in[18]; const float* b0  = (const float*)d_in[19];
  const float* w1  = (const float*)d_in[20]; const float* b1  = (const float*)d_in[21];
  const float* w2  = (const float*)d_in[22]; const float* b2  = (const float*)d_in[23];

  char* ws = (char*)d_ws;
  size_t off = 0;
  auto alloc = [&](size_t bytes) { void* p = ws + off; off += (bytes + 255) & ~(size_t)255; return p; };

  unsigned long long* maskU = (unsigned long long*)alloc(3 * (size_t)N_NODES * MASK_ULL * 8);
  bf16* fbf   = (bf16*)alloc((size_t)N_NODES * D_IN * 2);
  bf16* w1b0  = (bf16*)alloc(HIDDEN * D_IN * 2);
  bf16* w1b1  = (bf16*)alloc(HIDDEN * D_IN * 2);
  bf16* w1b2  = (bf16*)alloc(HIDDEN * D_IN * 2);
  bf16* w2b0  = (bf16*)alloc(D_IN * HIDDEN * 2);
  bf16* w2b1  = (bf16*)alloc(D_IN * HIDDEN * 2);
  bf16* w2b2  = (bf16*)alloc(D_IN * HIDDEN * 2);
  bf16* wfusb = (bf16*)alloc(D_IN * C2 * 2);
  bf16* wf0b  = (bf16*)alloc(HIDDEN * D_IN * 2);
  bf16* wf1b  = (bf16*)alloc(HIDDEN * HIDDEN * 2);
  bf16* wf2b  = (bf16*)alloc(D_IN * HIDDEN * 2);
  bf16* g1    = (bf16*)alloc((size_t)N_NODES * C1 * 2);
  bf16* gP1   = (bf16*)alloc((size_t)N_NODES * C1 * 2);
  bf16* out1  = (bf16*)alloc((size_t)N_NODES * C1 * 2);
  bf16* g2    = (bf16*)alloc((size_t)N_NODES * C2 * 2);
  bf16* gP2   = (bf16*)alloc((size_t)N_NODES * C2 * 2);
  bf16* fusedB= (bf16*)alloc((size_t)N_NODES * C2 * 2);
  bf16* h0    = (bf16*)alloc((size_t)N_NODES * D_IN * 2);
  bf16* h1    = (bf16*)alloc((size_t)N_NODES * HIDDEN * 2);
  bf16* h2    = (bf16*)alloc((size_t)N_NODES * HIDDEN * 2);
  float* sl1  = (float*)alloc(18 * N_NODES * 4);
  float* sr1  = (float*)alloc(18 * N_NODES * 4);
  float* sl2  = (float*)alloc(3 * N_NODES * 4);
  float* sr2  = (float*)alloc(3 * N_NODES * 4);
  // partial buffers: att1 (36 slots) and att2 (24 slots) phases don't overlap -> union
  float* accU = (float*)alloc((size_t)18 * MAXQ * N_NODES * 64 * 4);  // 28.3 MB
  float* lU   = (float*)alloc((size_t)18 * MAXQ * N_NODES * 4);
  // zero-initialized region: colmeans only
  size_t zoff = off;
  float* gm1  = (float*)alloc(C1 * 4);
  float* gm2  = (float*)alloc(C2 * 4);
  size_t zbytes = off - zoff;
  const unsigned char* maskBytes = (const unsigned char*)maskU;

  hipMemsetAsync(ws + zoff, 0, zbytes, stream);

  // 1) casts
  CastArgs ca;
  {
    const float* srcs[11] = { feature, W1s, W1e, W1d, W2s, W2e, W2d, fW, w0, w1, w2 };
    bf16* dsts[11] = { fbf, w1b0, w1b1, w1b2, w2b0, w2b1, w2b2, wfusb, wf0b, wf1b, wf2b };
    int counts[11] = { N_NODES*D_IN, HIDDEN*D_IN, HIDDEN*D_IN, HIDDEN*D_IN,
                       D_IN*HIDDEN, D_IN*HIDDEN, D_IN*HIDDEN, D_IN*C2,
                       HIDDEN*D_IN, HIDDEN*HIDDEN, D_IN*HIDDEN };
    int cum = 0;
    for (int k = 0; k < 11; ++k) { ca.src[k] = srcs[k]; ca.dst[k] = dsts[k]; ca.cum4[k] = cum; cum += counts[k] / 4; }
    ca.cum4[11] = cum;
    cast_all_kernel<<<cum / 256, 256, 0, stream>>>(ca);
  }
  // 2) pack adjacency bits (3 per-branch masks, range folded in)
  pack_adj_kernel<<<N_NODES, 256, 0, stream>>>(adj, maskU, dnum, snum);
  // 3) g1 = f @ W1^T (3 branches via z)
  gemm64_kernel<false,false,false,false><<<dim3(48,6,3), 256, 0, stream>>>(
      fbf, D_IN, 0, w1b0, w1b1, w1b2, D_IN, g1, C1, HIDDEN, D_IN, nullptr, nullptr);
  // 4) pack g1 -> gP1
  pack_kernel<C1><<<dim3(48,18), 256, 0, stream>>>(g1, gP1);
  // 5) sl/sr layer1 (prescaled by log2e)
  head_proj_kernel<HEADS, NH1><<<18 * N_NODES / 256, 256, 0, stream>>>(g1, C1, a1s, a1e, a1d, sl1, sr1);
  // 6) colmean g1
  colmean_kernel<<<dim3((C1 + 255) / 256, 24), 256, 0, stream>>>(g1, C1, gm1);
  // 7) attention 1 partials
  att_kernel<true><<<dim3(48, 18, MAXQ), 256, 0, stream>>>(gP1, sl1, sr1, maskBytes, dnum, snum, accU, lU);
  // 7b) finalize 1 (+ELU)
  fin1_kernel<<<N_NODES * (C1 / 8) / 256, 256, 0, stream>>>(accU, lU, gm1, dnum, snum, out1);
  // 8) g2 = out1 @ W2^T per branch
  gemm64_kernel<false,false,false,false><<<dim3(48,4,3), 256, 0, stream>>>(
      out1, C1, HIDDEN, w2b0, w2b1, w2b2, HIDDEN, g2, C2, D_IN, HIDDEN, nullptr, nullptr);
  // 9) pack g2 -> gP2
  pack_kernel<C2><<<dim3(48,12), 256, 0, stream>>>(g2, gP2);
  // 10) sl/sr layer2
  head_proj_kernel<1, D_IN><<<3 * N_NODES / 256, 256, 0, stream>>>(g2, C2, a2s, a2e, a2d, sl2, sr2);
  // 11) colmean g2
  colmean_kernel<<<dim3((C2 + 255) / 256, 24), 256, 0, stream>>>(g2, C2, gm2);
  // 12) attention 2 partials (combos = branch x 4 f-chunks)
  att_kernel<false><<<dim3(48, 12, MAXQ), 256, 0, stream>>>(gP2, sl2, sr2, maskBytes, dnum, snum, accU, lU);
  // 12b) finalize 2 (+residual, writes fused [doc,sect,sent])
  fin2_kernel<<<N_NODES * (C2 / 8) / 256, 256, 0, stream>>>(accU, lU, gm2, feature, dnum, snum, fusedB);
  // 13) fusion: h0 = leaky(fused @ fW^T + fB)
  gemm64_kernel<true,true,false,false><<<dim3(48,4,1), 256, 0, stream>>>(
      fusedB, C2, 0, wfusb, wfusb, wfusb, C2, h0, D_IN, 0, C2, fB, nullptr);
  // 14) ffn0: h1 = leaky(h0 @ w0^T + b0)
  gemm64_kernel<true,true,false,false><<<dim3(48,6,1), 256, 0, stream>>>(
      h0, D_IN, 0, wf0b, wf0b, wf0b, D_IN, h1, HIDDEN, 0, D_IN, b0, nullptr);
  // 15) ffn1: h2 = leaky(h1 @ w1^T + b1)
  gemm64_kernel<true,true,false,false><<<dim3(48,6,1), 256, 0, stream>>>(
      h1, HIDDEN, 0, wf1b, wf1b, wf1b, HIDDEN, h2, HIDDEN, 0, HIDDEN, b1, nullptr);
  // 16) ffn2: out = leaky(h2 @ w2^T + b2) + f   (fp32 out)
  gemm64_kernel<true,true,true,true><<<dim3(48,4,1), 256, 0, stream>>>(
      h2, HIDDEN, 0, wf2b, wf2b, wf2b, HIDDEN, d_out, D_IN, 0, HIDDEN, b2, feature);
}